// Round 2
// baseline (4379.959 us; speedup 1.0000x reference)
//
#include <hip/hip_runtime.h>
#include <hip/hip_bf16.h>

// Problem constants
#define BB 2
#define LL 2048
#define DD 512
#define HH 8
#define HDM 64
#define WIN 1536                      // D*3 im2col window
#define SCALE 0.022097086912079608f   // 1/sqrt(2048)

typedef __hip_bfloat16 bf16;
typedef unsigned short u16;

// Input element counts
#define XN  2097152    // 2*2048*512
#define WN  2359296    // 1536*512*3
#define BN  1536
#define FWN 262144     // 512*512
#define FBN 512

__device__ __forceinline__ float b2f(u16 u) {
    return __uint_as_float(((unsigned int)u) << 16);
}
__device__ __forceinline__ u16 f2u(float f) {
    bf16 h = __float2bfloat16(f);
    u16 r;
    __builtin_memcpy(&r, &h, 2);
    return r;
}
__device__ __forceinline__ void unpack8(uint4 p, float* f) {
    f[0] = __uint_as_float(p.x << 16); f[1] = __uint_as_float(p.x & 0xffff0000u);
    f[2] = __uint_as_float(p.y << 16); f[3] = __uint_as_float(p.y & 0xffff0000u);
    f[4] = __uint_as_float(p.z << 16); f[5] = __uint_as_float(p.z & 0xffff0000u);
    f[6] = __uint_as_float(p.w << 16); f[7] = __uint_as_float(p.w & 0xffff0000u);
}
__device__ __forceinline__ uint4 pack8(const float* f) {
    uint4 p;
    p.x = (unsigned)f2u(f[0]) | ((unsigned)f2u(f[1]) << 16);
    p.y = (unsigned)f2u(f[2]) | ((unsigned)f2u(f[3]) << 16);
    p.z = (unsigned)f2u(f[4]) | ((unsigned)f2u(f[5]) << 16);
    p.w = (unsigned)f2u(f[6]) | ((unsigned)f2u(f[7]) << 16);
    return p;
}

// -------------------------------------------------------------------------
// Kernel 0: dtype detect. Interpret first 256 half-words of x as bf16.
// f32 data -> low mantissa halves decode to wild exponents / NaN -> flag=1.
// bf16 data -> all |v| < 6 -> flag=0.
// -------------------------------------------------------------------------
__global__ void detect_kernel(const u16* __restrict__ x, int* __restrict__ flag) {
    int bad = 0;
    for (int i = threadIdx.x; i < 256; i += 64) {
        float v = b2f(x[i]);
        if (!(fabsf(v) < 100.f)) bad = 1;   // catches NaN too
    }
    unsigned long long m = __ballot(bad);
    if (threadIdx.x == 0) *flag = (m != 0ull) ? 1 : 0;
}

// -------------------------------------------------------------------------
// Kernel 0b: canonicalize an input tensor to bf16 (copy or f32->bf16).
// 8 elements per thread, n % 8 == 0 for all our inputs.
// -------------------------------------------------------------------------
__global__ __launch_bounds__(256) void convert_kernel(
    const void* __restrict__ src, u16* __restrict__ dst, int n,
    const int* __restrict__ flagp)
{
    const int flag = *flagp;
    int i = (blockIdx.x * 256 + threadIdx.x) * 8;
    if (i >= n) return;
    if (flag) {
        const float* s = (const float*)src;
        float f[8];
        float4 a = *(const float4*)(s + i);
        float4 b = *(const float4*)(s + i + 4);
        f[0] = a.x; f[1] = a.y; f[2] = a.z; f[3] = a.w;
        f[4] = b.x; f[5] = b.y; f[6] = b.z; f[7] = b.w;
        *(uint4*)(dst + i) = pack8(f);
    } else {
        *(uint4*)(dst + i) = *(const uint4*)((const u16*)src + i);
    }
}

// -------------------------------------------------------------------------
// Kernel 1: conv1d(k=3,pad=1) + bias + swish -> qkv [b][h][t][d][l] bf16
// One block = (b, 8 consecutive l). 256 threads, each computes 6 channels.
// Weight row for channel o is contiguous over (i*3+k) — identical ordering
// to the im2col window staged in LDS, so the conv is a plain 1536-dot.
// -------------------------------------------------------------------------
__global__ __launch_bounds__(256) void conv_swish_kernel(
    const u16* __restrict__ x,      // [B][L][D] bf16 canonical
    const u16* __restrict__ w,      // [1536][512][3] bf16 canonical
    const u16* __restrict__ bias,   // [1536]
    u16* __restrict__ qkv)          // [B][H][3][HD][L] bf16
{
    __shared__ float xwin[8 * WIN];  // [l][i*3+k]
    const int blk = blockIdx.x;          // b*256 + ltile
    const int b  = blk >> 8;
    const int l0 = (blk & 255) * 8;
    const int tid = threadIdx.x;

    for (int e = tid; e < 8 * WIN; e += 256) {
        int l   = e / WIN;
        int rem = e - l * WIN;
        int i   = rem / 3;
        int k   = rem - i * 3;
        int row = l0 + l + k - 1;
        float val = 0.f;
        if (row >= 0 && row < LL) val = b2f(x[(b * LL + row) * DD + i]);
        xwin[e] = val;
    }
    __syncthreads();

    float acc[6][8];
#pragma unroll
    for (int c = 0; c < 6; ++c)
#pragma unroll
        for (int l = 0; l < 8; ++l) acc[c][l] = 0.f;

    for (int widx = 0; widx < WIN; widx += 8) {
        float wv[6][8];
#pragma unroll
        for (int c = 0; c < 6; ++c) {
            uint4 p = *(const uint4*)(w + (size_t)(c * 256 + tid) * WIN + widx);
            unpack8(p, wv[c]);
        }
#pragma unroll
        for (int l = 0; l < 8; ++l) {
            float xv[8];
            float4 a0 = *(const float4*)&xwin[l * WIN + widx];
            float4 a1 = *(const float4*)&xwin[l * WIN + widx + 4];
            xv[0] = a0.x; xv[1] = a0.y; xv[2] = a0.z; xv[3] = a0.w;
            xv[4] = a1.x; xv[5] = a1.y; xv[6] = a1.z; xv[7] = a1.w;
#pragma unroll
            for (int c = 0; c < 6; ++c)
#pragma unroll
                for (int j = 0; j < 8; ++j)
                    acc[c][l] = fmaf(wv[c][j], xv[j], acc[c][l]);
        }
    }

#pragma unroll
    for (int c = 0; c < 6; ++c) {
        int o  = c * 256 + tid;
        float bb = b2f(bias[o]);
        int hh = o / 192;
        int rr = o - hh * 192;
        int t  = rr >> 6;
        int dd = rr & 63;
        u16* dst = qkv + ((size_t)(((b * HH + hh) * 3 + t) * HDM + dd)) * LL + l0;
        float y8[8];
#pragma unroll
        for (int l = 0; l < 8; ++l) {
            float y = acc[c][l] + bb;
            y8[l] = y / (1.f + __expf(-y));   // swish
        }
        *(uint4*)dst = pack8(y8);
    }
}

// -------------------------------------------------------------------------
// Kernel 2: attention per (b,h): softmax(q^T k / sqrt(L)) v^T
// Block = (b, h, 16 queries). 256 threads = 16 ty (query) x 16 tx (m-lane).
// Online softmax over each thread's m-subset (8-wide bf16 chunks), then
// flash-merge across the 16 tx lanes via shfl_xor.
// -------------------------------------------------------------------------
__global__ __launch_bounds__(256) void attn_kernel(
    const u16* __restrict__ qkv,   // [B][H][3][HD][L] bf16
    u16* __restrict__ newv)        // [B][L][H*HD] bf16
{
    const int blk = blockIdx.x;              // bh*128 + wt
    const int wt = blk & 127;
    const int bh = blk >> 7;                 // b*H + h
    const int b  = bh >> 3;
    const int h  = bh & 7;
    const u16* qb = qkv + ((size_t)(bh * 3 + 0)) * HDM * LL;
    const u16* kb = qkv + ((size_t)(bh * 3 + 1)) * HDM * LL;
    const u16* vb = qkv + ((size_t)(bh * 3 + 2)) * HDM * LL;
    const int w0 = wt * 16;
    const int tid = threadIdx.x;

    __shared__ float qs[16][64];
    for (int e = tid; e < 1024; e += 256) {
        int ww = e >> 6, d = e & 63;
        qs[ww][d] = b2f(qb[d * LL + w0 + ww]);
    }
    __syncthreads();

    const int tx = tid & 15, ty = tid >> 4;

    float qreg[64];
#pragma unroll
    for (int d = 0; d < 64; ++d) qreg[d] = qs[ty][d] * SCALE;  // fold scale

    float m_run = -1e30f, l_run = 0.f;
    float acc[64];
#pragma unroll
    for (int d = 0; d < 64; ++d) acc[d] = 0.f;

    for (int oc = 0; oc < 8; ++oc) {        // 8 chunks of 256 m
        float s[16];
#pragma unroll
        for (int g = 0; g < 2; ++g) {       // 2 groups of 128 m; 8 m per lane
            int m = oc * 256 + g * 128 + tx * 8;
            float sj[8];
#pragma unroll
            for (int j = 0; j < 8; ++j) sj[j] = 0.f;
#pragma unroll
            for (int d = 0; d < 64; ++d) {
                uint4 p = *(const uint4*)(kb + (size_t)d * LL + m);
                float kf[8];
                unpack8(p, kf);
                float qd = qreg[d];
#pragma unroll
                for (int j = 0; j < 8; ++j) sj[j] = fmaf(qd, kf[j], sj[j]);
            }
#pragma unroll
            for (int j = 0; j < 8; ++j) s[g * 8 + j] = sj[j];
        }
        float cmax = s[0];
#pragma unroll
        for (int j = 1; j < 16; ++j) cmax = fmaxf(cmax, s[j]);
        float m_new = fmaxf(m_run, cmax);
        float f = __expf(m_run - m_new);
        l_run *= f;
#pragma unroll
        for (int d = 0; d < 64; ++d) acc[d] *= f;
        m_run = m_new;

#pragma unroll
        for (int g = 0; g < 2; ++g) {
            int m = oc * 256 + g * 128 + tx * 8;
            float p8[8];
#pragma unroll
            for (int j = 0; j < 8; ++j) {
                p8[j] = __expf(s[g * 8 + j] - m_new);
                l_run += p8[j];
            }
#pragma unroll
            for (int d = 0; d < 64; ++d) {
                uint4 p = *(const uint4*)(vb + (size_t)d * LL + m);
                float vf[8];
                unpack8(p, vf);
#pragma unroll
                for (int j = 0; j < 8; ++j) acc[d] = fmaf(p8[j], vf[j], acc[d]);
            }
        }
    }

    // flash-merge across the 16 tx lanes (low 4 lane bits of the wave)
#pragma unroll
    for (int mask = 8; mask >= 1; mask >>= 1) {
        float m_o = __shfl_xor(m_run, mask);
        float l_o = __shfl_xor(l_run, mask);
        float m_new = fmaxf(m_run, m_o);
        float fa = __expf(m_run - m_new);
        float fb = __expf(m_o - m_new);
        l_run = l_run * fa + l_o * fb;
#pragma unroll
        for (int d = 0; d < 64; ++d) {
            float a_o = __shfl_xor(acc[d], mask);
            acc[d] = acc[d] * fa + a_o * fb;
        }
        m_run = m_new;
    }

    if (tx == 0) {
        float inv = 1.f / l_run;
        int w = w0 + ty;
        u16* outp = newv + ((size_t)(b * LL + w)) * 512 + h * 64;
#pragma unroll
        for (int d = 0; d < 64; d += 8) {
            float o8[8];
#pragma unroll
            for (int j = 0; j < 8; ++j) o8[j] = acc[d + j] * inv;
            *(uint4*)(outp + d) = pack8(o8);
        }
    }
}

// -------------------------------------------------------------------------
// Kernel 3: m = swish(newv @ fc_w^T + fc_b); out = layernorm(2x + m)
// One block per (b,l) row. 256 threads, 2 output dims each.
// Output dtype follows input dtype (flag).
// -------------------------------------------------------------------------
__global__ __launch_bounds__(256) void fc_ln_kernel(
    const u16* __restrict__ newv,    // [B*L][512] bf16
    const u16* __restrict__ fcw,     // [512][512] bf16
    const u16* __restrict__ fcb,     // [512]
    const u16* __restrict__ x,       // [B][L][D] bf16 canonical
    void* __restrict__ out,          // bf16 or f32 per flag
    const int* __restrict__ flagp)
{
    const int bl = blockIdx.x;     // b*L + l
    const int tid = threadIdx.x;
    __shared__ float nv[512];
    __shared__ float ssum[4], ssq[4];

    nv[tid]       = b2f(newv[(size_t)bl * 512 + tid]);
    nv[tid + 256] = b2f(newv[(size_t)bl * 512 + tid + 256]);
    __syncthreads();

    float r[2];
#pragma unroll
    for (int c = 0; c < 2; ++c) {
        int dout = c * 256 + tid;
        const u16* wr = fcw + (size_t)dout * 512;
        float a = 0.f;
        for (int j = 0; j < 512; j += 8) {
            uint4 p = *(const uint4*)(wr + j);
            float f[8];
            unpack8(p, f);
#pragma unroll
            for (int q = 0; q < 8; ++q) a = fmaf(f[q], nv[j + q], a);
        }
        a += b2f(fcb[dout]);
        float sw = a / (1.f + __expf(-a));        // swish
        float xv = b2f(x[(size_t)bl * 512 + dout]);
        r[c] = xv * 2.f + sw;
    }

    // layernorm over 512 values
    float s  = r[0] + r[1];
    float sq = r[0] * r[0] + r[1] * r[1];
#pragma unroll
    for (int mask = 32; mask >= 1; mask >>= 1) {
        s  += __shfl_xor(s, mask);
        sq += __shfl_xor(sq, mask);
    }
    const int lane = tid & 63, wid = tid >> 6;
    if (lane == 0) { ssum[wid] = s; ssq[wid] = sq; }
    __syncthreads();
    s  = ssum[0] + ssum[1] + ssum[2] + ssum[3];
    sq = ssq[0] + ssq[1] + ssq[2] + ssq[3];
    float mu  = s * (1.f / 512.f);
    float var = sq * (1.f / 512.f) - mu * mu;
    float inv = rsqrtf(var + 1e-5f);

    const int flag = *flagp;
#pragma unroll
    for (int c = 0; c < 2; ++c) {
        int dout = c * 256 + tid;
        float val = (r[c] - mu) * inv;
        if (flag) ((float*)out)[(size_t)bl * 512 + dout] = val;
        else      ((u16*)out)[(size_t)bl * 512 + dout] = f2u(val);
    }
}

extern "C" void kernel_launch(void* const* d_in, const int* in_sizes, int n_in,
                              void* d_out, int out_size, void* d_ws, size_t ws_size,
                              hipStream_t stream) {
    (void)in_sizes; (void)n_in; (void)out_size; (void)ws_size;

    char* ws = (char*)d_ws;
    int* flag = (int*)ws;
    u16* xc   = (u16*)(ws + 256);
    u16* wc   = xc + XN;
    u16* bc   = wc + WN;
    u16* fwc  = bc + BN;
    u16* fbc  = fwc + FWN;
    u16* qkvc = (u16*)(ws + 9441536);    // 6,291,456 bf16 -> ends 22,024,448
    u16* nvc  = (u16*)(ws + 22024448);   // 2,097,152 bf16 -> ends 26,218,752

    detect_kernel<<<dim3(1), dim3(64), 0, stream>>>((const u16*)d_in[0], flag);

    convert_kernel<<<dim3((XN + 2047) / 2048), dim3(256), 0, stream>>>(d_in[0], xc,  XN,  flag);
    convert_kernel<<<dim3((WN + 2047) / 2048), dim3(256), 0, stream>>>(d_in[1], wc,  WN,  flag);
    convert_kernel<<<dim3((BN + 2047) / 2048), dim3(256), 0, stream>>>(d_in[2], bc,  BN,  flag);
    convert_kernel<<<dim3((FWN + 2047) / 2048), dim3(256), 0, stream>>>(d_in[3], fwc, FWN, flag);
    convert_kernel<<<dim3((FBN + 2047) / 2048), dim3(256), 0, stream>>>(d_in[4], fbc, FBN, flag);

    conv_swish_kernel<<<dim3(BB * (LL / 8)), dim3(256), 0, stream>>>(xc, wc, bc, qkvc);
    attn_kernel<<<dim3(BB * HH * (LL / 16)), dim3(256), 0, stream>>>(qkvc, nvc);
    fc_ln_kernel<<<dim3(BB * LL), dim3(256), 0, stream>>>(nvc, fwc, fbc, xc, d_out, flag);
}

// Round 3
// 1009.158 us; speedup vs baseline: 4.3402x; 4.3402x over previous
//
#include <hip/hip_runtime.h>
#include <hip/hip_bf16.h>

// Problem constants
#define BB 2
#define LL 2048
#define DD 512
#define HH 8
#define HDM 64
#define WIN 1536                      // D*3 im2col window
#define SCALE 0.022097086912079608f   // 1/sqrt(2048)

typedef __hip_bfloat16 bf16;
typedef unsigned short u16;
typedef __attribute__((ext_vector_type(8))) short short8v;   // 8 bf16 (4 VGPRs)
typedef __attribute__((ext_vector_type(4))) float float4v;   // 4 fp32 acc

// Input element counts
#define XN  2097152    // 2*2048*512
#define WN  2359296    // 1536*512*3
#define BN  1536
#define FWN 262144     // 512*512
#define FBN 512

__device__ __forceinline__ float b2f(u16 u) {
    return __uint_as_float(((unsigned int)u) << 16);
}
__device__ __forceinline__ u16 f2u(float f) {
    bf16 h = __float2bfloat16(f);
    u16 r;
    __builtin_memcpy(&r, &h, 2);
    return r;
}
__device__ __forceinline__ void unpack8(uint4 p, float* f) {
    f[0] = __uint_as_float(p.x << 16); f[1] = __uint_as_float(p.x & 0xffff0000u);
    f[2] = __uint_as_float(p.y << 16); f[3] = __uint_as_float(p.y & 0xffff0000u);
    f[4] = __uint_as_float(p.z << 16); f[5] = __uint_as_float(p.z & 0xffff0000u);
    f[6] = __uint_as_float(p.w << 16); f[7] = __uint_as_float(p.w & 0xffff0000u);
}
__device__ __forceinline__ uint4 pack8(const float* f) {
    uint4 p;
    p.x = (unsigned)f2u(f[0]) | ((unsigned)f2u(f[1]) << 16);
    p.y = (unsigned)f2u(f[2]) | ((unsigned)f2u(f[3]) << 16);
    p.z = (unsigned)f2u(f[4]) | ((unsigned)f2u(f[5]) << 16);
    p.w = (unsigned)f2u(f[6]) | ((unsigned)f2u(f[7]) << 16);
    return p;
}

// -------------------------------------------------------------------------
// Kernel 0: dtype detect (f32 vs bf16 inputs). See R1 notes.
// -------------------------------------------------------------------------
__global__ void detect_kernel(const u16* __restrict__ x, int* __restrict__ flag) {
    int bad = 0;
    for (int i = threadIdx.x; i < 256; i += 64) {
        float v = b2f(x[i]);
        if (!(fabsf(v) < 100.f)) bad = 1;   // catches NaN too
    }
    unsigned long long m = __ballot(bad);
    if (threadIdx.x == 0) *flag = (m != 0ull) ? 1 : 0;
}

// -------------------------------------------------------------------------
// Kernel 0b: canonicalize an input tensor to bf16 (copy or f32->bf16).
// -------------------------------------------------------------------------
__global__ __launch_bounds__(256) void convert_kernel(
    const void* __restrict__ src, u16* __restrict__ dst, int n,
    const int* __restrict__ flagp)
{
    const int flag = *flagp;
    int i = (blockIdx.x * 256 + threadIdx.x) * 8;
    if (i >= n) return;
    if (flag) {
        const float* s = (const float*)src;
        float f[8];
        float4 a = *(const float4*)(s + i);
        float4 b = *(const float4*)(s + i + 4);
        f[0] = a.x; f[1] = a.y; f[2] = a.z; f[3] = a.w;
        f[4] = b.x; f[5] = b.y; f[6] = b.z; f[7] = b.w;
        *(uint4*)(dst + i) = pack8(f);
    } else {
        *(uint4*)(dst + i) = *(const uint4*)((const u16*)src + i);
    }
}

// -------------------------------------------------------------------------
// Kernel 1: conv1d(k=3,pad=1) + bias + swish.
// Q,K -> qkbuf [bh][t][l][64] (row-major per head, SCALE folded into Q)
// V   -> vbuf  [bh][64][l]    (d-major)
// -------------------------------------------------------------------------
__global__ __launch_bounds__(256) void conv_swish_kernel(
    const u16* __restrict__ x,      // [B][L][D] bf16 canonical
    const u16* __restrict__ w,      // [1536][512][3] bf16 canonical
    const u16* __restrict__ bias,   // [1536]
    u16* __restrict__ qkbuf,        // [B*H][2][L][64]
    u16* __restrict__ vbuf)         // [B*H][64][L]
{
    __shared__ float xwin[8 * WIN];  // [l][i*3+k]
    const int blk = blockIdx.x;          // b*256 + ltile
    const int b  = blk >> 8;
    const int l0 = (blk & 255) * 8;
    const int tid = threadIdx.x;

    for (int e = tid; e < 8 * WIN; e += 256) {
        int l   = e / WIN;
        int rem = e - l * WIN;
        int i   = rem / 3;
        int k   = rem - i * 3;
        int row = l0 + l + k - 1;
        float val = 0.f;
        if (row >= 0 && row < LL) val = b2f(x[(b * LL + row) * DD + i]);
        xwin[e] = val;
    }
    __syncthreads();

    float acc[6][8];
#pragma unroll
    for (int c = 0; c < 6; ++c)
#pragma unroll
        for (int l = 0; l < 8; ++l) acc[c][l] = 0.f;

    for (int widx = 0; widx < WIN; widx += 8) {
        float wv[6][8];
#pragma unroll
        for (int c = 0; c < 6; ++c) {
            uint4 p = *(const uint4*)(w + (size_t)(c * 256 + tid) * WIN + widx);
            unpack8(p, wv[c]);
        }
#pragma unroll
        for (int l = 0; l < 8; ++l) {
            float xv[8];
            float4 a0 = *(const float4*)&xwin[l * WIN + widx];
            float4 a1 = *(const float4*)&xwin[l * WIN + widx + 4];
            xv[0] = a0.x; xv[1] = a0.y; xv[2] = a0.z; xv[3] = a0.w;
            xv[4] = a1.x; xv[5] = a1.y; xv[6] = a1.z; xv[7] = a1.w;
#pragma unroll
            for (int c = 0; c < 6; ++c)
#pragma unroll
                for (int j = 0; j < 8; ++j)
                    acc[c][l] = fmaf(wv[c][j], xv[j], acc[c][l]);
        }
    }

#pragma unroll
    for (int c = 0; c < 6; ++c) {
        int o  = c * 256 + tid;
        float bb = b2f(bias[o]);
        int hh = o / 192;
        int rr = o - hh * 192;
        int t  = rr >> 6;
        int dd = rr & 63;
        int bh = b * HH + hh;
        float y8[8];
#pragma unroll
        for (int l = 0; l < 8; ++l) {
            float y = acc[c][l] + bb;
            y8[l] = y / (1.f + __expf(-y));   // swish
        }
        if (t == 2) {
            u16* dst = vbuf + ((size_t)bh * HDM + dd) * LL + l0;
            *(uint4*)dst = pack8(y8);
        } else {
            if (t == 0) {
#pragma unroll
                for (int l = 0; l < 8; ++l) y8[l] *= SCALE;  // fold score scale into Q
            }
            u16* dst = qkbuf + ((size_t)(bh * 2 + t) * LL + l0) * HDM + dd;
#pragma unroll
            for (int l = 0; l < 8; ++l) dst[(size_t)l * HDM] = f2u(y8[l]);
        }
    }
}

// -------------------------------------------------------------------------
// Kernel 2: MFMA flash attention per (b,h).
// Block = 4 waves x 16 queries = 64 queries; loop m in 64-chunks.
// S = Q·K^T via mfma_16x16x32_bf16 (A from Q rows, B from K rows);
// online softmax on C-layout (row=quad*4+reg, col=lane&15);
// P transposed C->A layout via per-wave LDS tile; PV B-operand from V[d][m].
// LDS rows padded to 72 u16 -> b128 frag reads are conflict-free
// (bank group = 4*((l16+quad)%8), 8 lanes per group).
// -------------------------------------------------------------------------
__global__ __launch_bounds__(256) void attn_mfma_kernel(
    const u16* __restrict__ qk,    // [B*H][2][L][64]
    const u16* __restrict__ v,     // [B*H][64][L]
    u16* __restrict__ newv)        // [B][L][512]
{
    __shared__ u16 kts[2][64][72];   // [buf][m][d]
    __shared__ u16 vts[2][64][72];   // [buf][d][m]
    __shared__ u16 pts[4][16][72];   // per-wave P [w][m]

    const int blkid = blockIdx.x;        // bh*32 + wchunk
    const int bh = blkid >> 5;
    const int wc = blkid & 31;
    const int b  = bh >> 3;
    const int h  = bh & 7;
    const int tid  = threadIdx.x;
    const int wave = tid >> 6;
    const int lane = tid & 63;
    const int quad = lane >> 4;
    const int l16  = lane & 15;

    const u16* qbase = qk + ((size_t)(bh * 2 + 0)) * LL * HDM;
    const u16* kbase = qk + ((size_t)(bh * 2 + 1)) * LL * HDM;
    const u16* vbase = v + (size_t)bh * HDM * LL;

    const int w0 = wc * 64 + wave * 16;   // this wave's 16 queries

    // Q A-frags (once): lane reads Q[w0+l16][quad*8 + j] (+32 for k-half 1)
    short8v qfrag[2];
    qfrag[0] = *(const short8v*)(qbase + (size_t)(w0 + l16) * HDM + quad * 8);
    qfrag[1] = *(const short8v*)(qbase + (size_t)(w0 + l16) * HDM + 32 + quad * 8);

    float4v oacc[4];
#pragma unroll
    for (int dt = 0; dt < 4; ++dt) oacc[dt] = (float4v){0.f, 0.f, 0.f, 0.f};
    float m_run[4], l_run[4];
#pragma unroll
    for (int r = 0; r < 4; ++r) { m_run[r] = -1e30f; l_run[r] = 0.f; }

    // staging thread mapping: 512 uint4 per buffer, 2 per thread
    const int r0 = tid >> 3;          // rows 0..31
    const int r1 = r0 + 32;           // rows 32..63
    const int c8 = tid & 7;           // 8 uint4 per 64-elem row

    // prologue: stage chunk 0 into buf 0
    {
        uint4 ka  = *(const uint4*)(kbase + (size_t)r0 * HDM + c8 * 8);
        uint4 kb2 = *(const uint4*)(kbase + (size_t)r1 * HDM + c8 * 8);
        uint4 va  = *(const uint4*)(vbase + (size_t)r0 * LL + c8 * 8);
        uint4 vb2 = *(const uint4*)(vbase + (size_t)r1 * LL + c8 * 8);
        *(uint4*)&kts[0][r0][c8 * 8] = ka;
        *(uint4*)&kts[0][r1][c8 * 8] = kb2;
        *(uint4*)&vts[0][r0][c8 * 8] = va;
        *(uint4*)&vts[0][r1][c8 * 8] = vb2;
    }

    for (int ic = 0; ic < 32; ++ic) {
        const int cur = ic & 1;
        __syncthreads();   // staging(ic) visible; prev-iter readers done

        // prefetch next chunk into regs (latency hidden by S compute)
        uint4 ka, kb2, va, vb2;
        if (ic < 31) {
            const int m0n = (ic + 1) * 64;
            ka  = *(const uint4*)(kbase + (size_t)(m0n + r0) * HDM + c8 * 8);
            kb2 = *(const uint4*)(kbase + (size_t)(m0n + r1) * HDM + c8 * 8);
            va  = *(const uint4*)(vbase + (size_t)r0 * LL + m0n + c8 * 8);
            vb2 = *(const uint4*)(vbase + (size_t)r1 * LL + m0n + c8 * 8);
        }

        // S = Q·K^T : 4 m-tiles x 2 k-halves
        float4v s[4];
#pragma unroll
        for (int mt = 0; mt < 4; ++mt) {
            s[mt] = (float4v){0.f, 0.f, 0.f, 0.f};
            short8v b0 = *(const short8v*)&kts[cur][mt * 16 + l16][quad * 8];
            s[mt] = __builtin_amdgcn_mfma_f32_16x16x32_bf16(qfrag[0], b0, s[mt], 0, 0, 0);
            short8v b1 = *(const short8v*)&kts[cur][mt * 16 + l16][32 + quad * 8];
            s[mt] = __builtin_amdgcn_mfma_f32_16x16x32_bf16(qfrag[1], b1, s[mt], 0, 0, 0);
        }

        // store prefetched chunk into the other buffer
        if (ic < 31) {
            const int nb = 1 - cur;
            *(uint4*)&kts[nb][r0][c8 * 8] = ka;
            *(uint4*)&kts[nb][r1][c8 * 8] = kb2;
            *(uint4*)&vts[nb][r0][c8 * 8] = va;
            *(uint4*)&vts[nb][r1][c8 * 8] = vb2;
        }

        // online softmax (rows = quad*4+r, cols across 16 lanes of the quad)
        float rmax[4];
#pragma unroll
        for (int r = 0; r < 4; ++r)
            rmax[r] = fmaxf(fmaxf(s[0][r], s[1][r]), fmaxf(s[2][r], s[3][r]));
#pragma unroll
        for (int msk = 1; msk <= 8; msk <<= 1)
#pragma unroll
            for (int r = 0; r < 4; ++r)
                rmax[r] = fmaxf(rmax[r], __shfl_xor(rmax[r], msk));
        float alpha[4];
#pragma unroll
        for (int r = 0; r < 4; ++r) {
            float mnew = fmaxf(m_run[r], rmax[r]);
            alpha[r] = __expf(m_run[r] - mnew);
            m_run[r] = mnew;
            l_run[r] *= alpha[r];
        }
#pragma unroll
        for (int dt = 0; dt < 4; ++dt)
#pragma unroll
            for (int r = 0; r < 4; ++r) oacc[dt][r] *= alpha[r];

        float lsum[4] = {0.f, 0.f, 0.f, 0.f};
#pragma unroll
        for (int mt = 0; mt < 4; ++mt)
#pragma unroll
            for (int r = 0; r < 4; ++r) {
                float p = __expf(s[mt][r] - m_run[r]);
                s[mt][r] = p;
                lsum[r] += p;
            }
#pragma unroll
        for (int msk = 1; msk <= 8; msk <<= 1)
#pragma unroll
            for (int r = 0; r < 4; ++r) lsum[r] += __shfl_xor(lsum[r], msk);
#pragma unroll
        for (int r = 0; r < 4; ++r) l_run[r] += lsum[r];

        // P: C-layout -> LDS [w][m]
#pragma unroll
        for (int mt = 0; mt < 4; ++mt)
#pragma unroll
            for (int r = 0; r < 4; ++r)
                pts[wave][quad * 4 + r][mt * 16 + l16] = f2u(s[mt][r]);

        __syncthreads();   // P visible (cross-lane); staging writes drained

        // PV: A from P rows, B from V[d][m] rows (m-contiguous)
        short8v pa0 = *(const short8v*)&pts[wave][l16][quad * 8];
        short8v pa1 = *(const short8v*)&pts[wave][l16][32 + quad * 8];
#pragma unroll
        for (int dt = 0; dt < 4; ++dt) {
            short8v v0 = *(const short8v*)&vts[cur][dt * 16 + l16][quad * 8];
            oacc[dt] = __builtin_amdgcn_mfma_f32_16x16x32_bf16(pa0, v0, oacc[dt], 0, 0, 0);
            short8v v1 = *(const short8v*)&vts[cur][dt * 16 + l16][32 + quad * 8];
            oacc[dt] = __builtin_amdgcn_mfma_f32_16x16x32_bf16(pa1, v1, oacc[dt], 0, 0, 0);
        }
    }

    // epilogue: O[w][d] / l_run -> newv[b][w][h*64+d]
    float inv[4];
#pragma unroll
    for (int r = 0; r < 4; ++r) inv[r] = 1.f / l_run[r];
    u16* ob = newv + (size_t)b * LL * 512 + h * 64;
#pragma unroll
    for (int dt = 0; dt < 4; ++dt)
#pragma unroll
        for (int r = 0; r < 4; ++r) {
            int w = w0 + quad * 4 + r;
            ob[(size_t)w * 512 + dt * 16 + l16] = f2u(oacc[dt][r] * inv[r]);
        }
}

// -------------------------------------------------------------------------
// Kernel 3: m = swish(newv @ fc_w^T + fc_b); out = layernorm(2x + m)
// -------------------------------------------------------------------------
__global__ __launch_bounds__(256) void fc_ln_kernel(
    const u16* __restrict__ newv,    // [B*L][512] bf16
    const u16* __restrict__ fcw,     // [512][512] bf16
    const u16* __restrict__ fcb,     // [512]
    const u16* __restrict__ x,       // [B][L][D] bf16 canonical
    void* __restrict__ out,          // bf16 or f32 per flag
    const int* __restrict__ flagp)
{
    const int bl = blockIdx.x;     // b*L + l
    const int tid = threadIdx.x;
    __shared__ float nv[512];
    __shared__ float ssum[4], ssq[4];

    nv[tid]       = b2f(newv[(size_t)bl * 512 + tid]);
    nv[tid + 256] = b2f(newv[(size_t)bl * 512 + tid + 256]);
    __syncthreads();

    float r[2];
#pragma unroll
    for (int c = 0; c < 2; ++c) {
        int dout = c * 256 + tid;
        const u16* wr = fcw + (size_t)dout * 512;
        float a = 0.f;
        for (int j = 0; j < 512; j += 8) {
            uint4 p = *(const uint4*)(wr + j);
            float f[8];
            unpack8(p, f);
#pragma unroll
            for (int q = 0; q < 8; ++q) a = fmaf(f[q], nv[j + q], a);
        }
        a += b2f(fcb[dout]);
        float sw = a / (1.f + __expf(-a));        // swish
        float xv = b2f(x[(size_t)bl * 512 + dout]);
        r[c] = xv * 2.f + sw;
    }

    float s  = r[0] + r[1];
    float sq = r[0] * r[0] + r[1] * r[1];
#pragma unroll
    for (int mask = 32; mask >= 1; mask >>= 1) {
        s  += __shfl_xor(s, mask);
        sq += __shfl_xor(sq, mask);
    }
    const int lane = tid & 63, wid = tid >> 6;
    if (lane == 0) { ssum[wid] = s; ssq[wid] = sq; }
    __syncthreads();
    s  = ssum[0] + ssum[1] + ssum[2] + ssum[3];
    sq = ssq[0] + ssq[1] + ssq[2] + ssq[3];
    float mu  = s * (1.f / 512.f);
    float var = sq * (1.f / 512.f) - mu * mu;
    float inv = rsqrtf(var + 1e-5f);

    const int flag = *flagp;
#pragma unroll
    for (int c = 0; c < 2; ++c) {
        int dout = c * 256 + tid;
        float val = (r[c] - mu) * inv;
        if (flag) ((float*)out)[(size_t)bl * 512 + dout] = val;
        else      ((u16*)out)[(size_t)bl * 512 + dout] = f2u(val);
    }
}

extern "C" void kernel_launch(void* const* d_in, const int* in_sizes, int n_in,
                              void* d_out, int out_size, void* d_ws, size_t ws_size,
                              hipStream_t stream) {
    (void)in_sizes; (void)n_in; (void)out_size; (void)ws_size;

    char* ws = (char*)d_ws;
    int* flag = (int*)ws;
    u16* xc   = (u16*)(ws + 256);
    u16* wc   = xc + XN;
    u16* bc   = wc + WN;
    u16* fwc  = bc + BN;
    u16* fbc  = fwc + FWN;
    u16* qkb  = (u16*)(ws + 9441536);    // [16][2][2048][64] = 8 MB  -> ends 17,830,144
    u16* vb   = (u16*)(ws + 17830144);   // [16][64][2048]    = 4 MB  -> ends 22,024,448
    u16* nvc  = (u16*)(ws + 22024448);   // [2][2048][512]    = 4 MB  -> ends 26,218,752

    detect_kernel<<<dim3(1), dim3(64), 0, stream>>>((const u16*)d_in[0], flag);

    convert_kernel<<<dim3((XN + 2047) / 2048), dim3(256), 0, stream>>>(d_in[0], xc,  XN,  flag);
    convert_kernel<<<dim3((WN + 2047) / 2048), dim3(256), 0, stream>>>(d_in[1], wc,  WN,  flag);
    convert_kernel<<<dim3((BN + 2047) / 2048), dim3(256), 0, stream>>>(d_in[2], bc,  BN,  flag);
    convert_kernel<<<dim3((FWN + 2047) / 2048), dim3(256), 0, stream>>>(d_in[3], fwc, FWN, flag);
    convert_kernel<<<dim3((FBN + 2047) / 2048), dim3(256), 0, stream>>>(d_in[4], fbc, FBN, flag);

    conv_swish_kernel<<<dim3(BB * (LL / 8)), dim3(256), 0, stream>>>(xc, wc, bc, qkb, vb);
    attn_mfma_kernel<<<dim3(BB * HH * (LL / 64)), dim3(256), 0, stream>>>(qkb, vb, nvc);
    fc_ln_kernel<<<dim3(BB * LL), dim3(256), 0, stream>>>(nvc, fwc, fbc, xc, d_out, flag);
}

// Round 4
// 545.220 us; speedup vs baseline: 8.0334x; 1.8509x over previous
//
#include <hip/hip_runtime.h>
#include <hip/hip_bf16.h>

// Problem constants
#define BB 2
#define LL 2048
#define DD 512
#define HH 8
#define HDM 64
#define SCALE 0.022097086912079608f   // 1/sqrt(2048)

typedef __hip_bfloat16 bf16;
typedef unsigned short u16;
typedef __attribute__((ext_vector_type(8))) short short8v;   // 8 bf16 (4 VGPRs)
typedef __attribute__((ext_vector_type(4))) float float4v;   // 4 fp32 acc

// Input element counts
#define XN  2097152    // 2*2048*512
#define WN  2359296    // 1536*512*3
#define BN  1536
#define FWN 262144     // 512*512
#define FBN 512

__device__ __forceinline__ float b2f(u16 u) {
    return __uint_as_float(((unsigned int)u) << 16);
}
__device__ __forceinline__ u16 f2u(float f) {
    bf16 h = __float2bfloat16(f);
    u16 r;
    __builtin_memcpy(&r, &h, 2);
    return r;
}
__device__ __forceinline__ void unpack8(uint4 p, float* f) {
    f[0] = __uint_as_float(p.x << 16); f[1] = __uint_as_float(p.x & 0xffff0000u);
    f[2] = __uint_as_float(p.y << 16); f[3] = __uint_as_float(p.y & 0xffff0000u);
    f[4] = __uint_as_float(p.z << 16); f[5] = __uint_as_float(p.z & 0xffff0000u);
    f[6] = __uint_as_float(p.w << 16); f[7] = __uint_as_float(p.w & 0xffff0000u);
}
__device__ __forceinline__ uint4 pack8(const float* f) {
    uint4 p;
    p.x = (unsigned)f2u(f[0]) | ((unsigned)f2u(f[1]) << 16);
    p.y = (unsigned)f2u(f[2]) | ((unsigned)f2u(f[3]) << 16);
    p.z = (unsigned)f2u(f[4]) | ((unsigned)f2u(f[5]) << 16);
    p.w = (unsigned)f2u(f[6]) | ((unsigned)f2u(f[7]) << 16);
    return p;
}

// -------------------------------------------------------------------------
// Kernel 0: dtype detect (f32 vs bf16 inputs). See R1 notes.
// -------------------------------------------------------------------------
__global__ void detect_kernel(const u16* __restrict__ x, int* __restrict__ flag) {
    int bad = 0;
    for (int i = threadIdx.x; i < 256; i += 64) {
        float v = b2f(x[i]);
        if (!(fabsf(v) < 100.f)) bad = 1;   // catches NaN too
    }
    unsigned long long m = __ballot(bad);
    if (threadIdx.x == 0) *flag = (m != 0ull) ? 1 : 0;
}

// -------------------------------------------------------------------------
// Kernel 0b: canonicalize an input tensor to bf16 (copy or f32->bf16).
// -------------------------------------------------------------------------
__global__ __launch_bounds__(256) void convert_kernel(
    const void* __restrict__ src, u16* __restrict__ dst, int n,
    const int* __restrict__ flagp)
{
    const int flag = *flagp;
    int i = (blockIdx.x * 256 + threadIdx.x) * 8;
    if (i >= n) return;
    if (flag) {
        const float* s = (const float*)src;
        float f[8];
        float4 a = *(const float4*)(s + i);
        float4 b = *(const float4*)(s + i + 4);
        f[0] = a.x; f[1] = a.y; f[2] = a.z; f[3] = a.w;
        f[4] = b.x; f[5] = b.y; f[6] = b.z; f[7] = b.w;
        *(uint4*)(dst + i) = pack8(f);
    } else {
        *(uint4*)(dst + i) = *(const uint4*)((const u16*)src + i);
    }
}

// -------------------------------------------------------------------------
// Kernel 0c: cnn_w canonicalize + transpose [o][i][k] -> [o][k*512+i].
// k-major K-index makes the conv-GEMM A-tile a contiguous slice of x.
// 294912 threads: (o, k, i8); 8 stride-3 reads, one uint4 write.
// -------------------------------------------------------------------------
__global__ __launch_bounds__(256) void convw_kernel(
    const void* __restrict__ src, u16* __restrict__ wt,
    const int* __restrict__ flagp)
{
    const int flag = *flagp;
    int idx = blockIdx.x * 256 + threadIdx.x;   // < 1536*3*64
    int i8  = idx & 63;
    int rem = idx >> 6;
    int k   = rem % 3;
    int o   = rem / 3;
    float f[8];
    if (flag) {
        const float* s = (const float*)src;
#pragma unroll
        for (int j = 0; j < 8; ++j) f[j] = s[(size_t)o * 1536 + (i8 * 8 + j) * 3 + k];
    } else {
        const u16* s = (const u16*)src;
#pragma unroll
        for (int j = 0; j < 8; ++j) f[j] = b2f(s[(size_t)o * 1536 + (i8 * 8 + j) * 3 + k]);
    }
    *(uint4*)(wt + (size_t)o * 1536 + k * 512 + i8 * 8) = pack8(f);
}

// -------------------------------------------------------------------------
// Kernel 1: conv1d(k=3,pad=1)+bias+swish as MFMA GEMM.
// C[4096 bl][1536 o] = im2col(x) @ wt^T, K = 1536 (k-major: kk = k*512+i).
// 128x128 tile, BK=64, 4 waves (2x2 of 64x64), double-buffered LDS +
// register prefetch, 1 barrier/chunk. Epilogue: bias+swish (+SCALE for Q),
// scatter to qkbuf [bh][t][l][64] (Q,K) / vbuf [bh][64][l] (V).
// -------------------------------------------------------------------------
__global__ __launch_bounds__(256) void conv_mfma_kernel(
    const u16* __restrict__ x,      // [B][L][512] bf16 canonical
    const u16* __restrict__ wt,     // [1536][1536] = [o][k*512+i]
    const u16* __restrict__ bias,   // [1536]
    u16* __restrict__ qkbuf,        // [B*H][2][L][64]
    u16* __restrict__ vbuf)         // [B*H][64][L]
{
    __shared__ u16 As[2][128][72];
    __shared__ u16 Bs[2][128][72];

    const int blk = blockIdx.x;          // rt*12 + ct
    const int rt = blk / 12;
    const int ct = blk - rt * 12;
    const int b  = rt >> 4;
    const int l0 = (rt & 15) * 128;
    const int tid  = threadIdx.x;
    const int wave = tid >> 6;
    const int lane = tid & 63;
    const int quad = lane >> 4;
    const int l16  = lane & 15;
    const int wx = wave & 1;             // n half
    const int wy = wave >> 1;            // m half

    const int sr = tid >> 3;             // staging row 0..31 (+32*j)
    const int sc = (tid & 7) * 8;        // staging col offset (elements)

    float4v acc[4][4];
#pragma unroll
    for (int mt = 0; mt < 4; ++mt)
#pragma unroll
        for (int nt = 0; nt < 4; ++nt) acc[mt][nt] = (float4v){0.f, 0.f, 0.f, 0.f};

    uint4 va[4], vb[4];
    // A loader for chunk kc: slab k = kc/8, i0 = (kc%8)*64, row = l0+r+k-1
    auto loadA = [&](int kc, uint4* v4) {
        int slab = kc >> 3;
        int i0 = (kc & 7) * 64;
#pragma unroll
        for (int j = 0; j < 4; ++j) {
            int gl = l0 + sr + j * 32 + slab - 1;
            uint4 z = {0u, 0u, 0u, 0u};
            v4[j] = (gl >= 0 && gl < LL)
                ? *(const uint4*)(x + ((size_t)(b * LL + gl)) * DD + i0 + sc) : z;
        }
    };
    auto loadB = [&](int kc, uint4* v4) {
#pragma unroll
        for (int j = 0; j < 4; ++j)
            v4[j] = *(const uint4*)(wt + (size_t)(ct * 128 + sr + j * 32) * 1536 + kc * 64 + sc);
    };
    auto store = [&](int buf, uint4* a4, uint4* b4) {
#pragma unroll
        for (int j = 0; j < 4; ++j) {
            *(uint4*)&As[buf][sr + j * 32][sc] = a4[j];
            *(uint4*)&Bs[buf][sr + j * 32][sc] = b4[j];
        }
    };

    loadA(0, va); loadB(0, vb);
    store(0, va, vb);

    for (int kc = 0; kc < 24; ++kc) {
        const int cur = kc & 1;
        __syncthreads();   // stores to cur visible; reads of 1-cur (prev iter) done

        if (kc < 23) { loadA(kc + 1, va); loadB(kc + 1, vb); }

#pragma unroll
        for (int half = 0; half < 2; ++half) {
            short8v aF[4], bF[4];
#pragma unroll
            for (int mt = 0; mt < 4; ++mt)
                aF[mt] = *(const short8v*)&As[cur][wy * 64 + mt * 16 + l16][half * 32 + quad * 8];
#pragma unroll
            for (int nt = 0; nt < 4; ++nt)
                bF[nt] = *(const short8v*)&Bs[cur][wx * 64 + nt * 16 + l16][half * 32 + quad * 8];
#pragma unroll
            for (int mt = 0; mt < 4; ++mt)
#pragma unroll
                for (int nt = 0; nt < 4; ++nt)
                    acc[mt][nt] = __builtin_amdgcn_mfma_f32_16x16x32_bf16(
                        aF[mt], bF[nt], acc[mt][nt], 0, 0, 0);
        }

        if (kc < 23) store(1 - cur, va, vb);
    }

    // epilogue: bias + swish (+SCALE for Q), scatter
#pragma unroll
    for (int nt = 0; nt < 4; ++nt) {
        int o = ct * 128 + wx * 64 + nt * 16 + l16;
        float bb = b2f(bias[o]);
        int hh = o / 192;
        int rr = o - hh * 192;
        int t  = rr >> 6;
        int dd = rr & 63;
        int bh = b * HH + hh;
#pragma unroll
        for (int mt = 0; mt < 4; ++mt)
#pragma unroll
            for (int r = 0; r < 4; ++r) {
                int l = l0 + wy * 64 + mt * 16 + quad * 4 + r;
                float y = acc[mt][nt][r] + bb;
                y = y / (1.f + __expf(-y));     // swish
                if (t == 2) {
                    vbuf[((size_t)(bh * HDM + dd)) * LL + l] = f2u(y);
                } else {
                    if (t == 0) y *= SCALE;     // fold score scale into Q
                    qkbuf[((size_t)((bh * 2 + t) * LL + l)) * HDM + dd] = f2u(y);
                }
            }
    }
}

// -------------------------------------------------------------------------
// Kernel 2: MFMA flash attention per (b,h). (unchanged from R3 — verified)
// -------------------------------------------------------------------------
__global__ __launch_bounds__(256) void attn_mfma_kernel(
    const u16* __restrict__ qk,    // [B*H][2][L][64]
    const u16* __restrict__ v,     // [B*H][64][L]
    u16* __restrict__ newv)        // [B][L][512]
{
    __shared__ u16 kts[2][64][72];   // [buf][m][d]
    __shared__ u16 vts[2][64][72];   // [buf][d][m]
    __shared__ u16 pts[4][16][72];   // per-wave P [w][m]

    const int blkid = blockIdx.x;        // bh*32 + wchunk
    const int bh = blkid >> 5;
    const int wc = blkid & 31;
    const int b  = bh >> 3;
    const int h  = bh & 7;
    const int tid  = threadIdx.x;
    const int wave = tid >> 6;
    const int lane = tid & 63;
    const int quad = lane >> 4;
    const int l16  = lane & 15;

    const u16* qbase = qk + ((size_t)(bh * 2 + 0)) * LL * HDM;
    const u16* kbase = qk + ((size_t)(bh * 2 + 1)) * LL * HDM;
    const u16* vbase = v + (size_t)bh * HDM * LL;

    const int w0 = wc * 64 + wave * 16;   // this wave's 16 queries

    short8v qfrag[2];
    qfrag[0] = *(const short8v*)(qbase + (size_t)(w0 + l16) * HDM + quad * 8);
    qfrag[1] = *(const short8v*)(qbase + (size_t)(w0 + l16) * HDM + 32 + quad * 8);

    float4v oacc[4];
#pragma unroll
    for (int dt = 0; dt < 4; ++dt) oacc[dt] = (float4v){0.f, 0.f, 0.f, 0.f};
    float m_run[4], l_run[4];
#pragma unroll
    for (int r = 0; r < 4; ++r) { m_run[r] = -1e30f; l_run[r] = 0.f; }

    const int r0 = tid >> 3;          // rows 0..31
    const int r1 = r0 + 32;           // rows 32..63
    const int c8 = tid & 7;           // 8 uint4 per 64-elem row

    {
        uint4 ka  = *(const uint4*)(kbase + (size_t)r0 * HDM + c8 * 8);
        uint4 kb2 = *(const uint4*)(kbase + (size_t)r1 * HDM + c8 * 8);
        uint4 va  = *(const uint4*)(vbase + (size_t)r0 * LL + c8 * 8);
        uint4 vb2 = *(const uint4*)(vbase + (size_t)r1 * LL + c8 * 8);
        *(uint4*)&kts[0][r0][c8 * 8] = ka;
        *(uint4*)&kts[0][r1][c8 * 8] = kb2;
        *(uint4*)&vts[0][r0][c8 * 8] = va;
        *(uint4*)&vts[0][r1][c8 * 8] = vb2;
    }

    for (int ic = 0; ic < 32; ++ic) {
        const int cur = ic & 1;
        __syncthreads();

        uint4 ka, kb2, va, vb2;
        if (ic < 31) {
            const int m0n = (ic + 1) * 64;
            ka  = *(const uint4*)(kbase + (size_t)(m0n + r0) * HDM + c8 * 8);
            kb2 = *(const uint4*)(kbase + (size_t)(m0n + r1) * HDM + c8 * 8);
            va  = *(const uint4*)(vbase + (size_t)r0 * LL + m0n + c8 * 8);
            vb2 = *(const uint4*)(vbase + (size_t)r1 * LL + m0n + c8 * 8);
        }

        float4v s[4];
#pragma unroll
        for (int mt = 0; mt < 4; ++mt) {
            s[mt] = (float4v){0.f, 0.f, 0.f, 0.f};
            short8v b0 = *(const short8v*)&kts[cur][mt * 16 + l16][quad * 8];
            s[mt] = __builtin_amdgcn_mfma_f32_16x16x32_bf16(qfrag[0], b0, s[mt], 0, 0, 0);
            short8v b1 = *(const short8v*)&kts[cur][mt * 16 + l16][32 + quad * 8];
            s[mt] = __builtin_amdgcn_mfma_f32_16x16x32_bf16(qfrag[1], b1, s[mt], 0, 0, 0);
        }

        if (ic < 31) {
            const int nb = 1 - cur;
            *(uint4*)&kts[nb][r0][c8 * 8] = ka;
            *(uint4*)&kts[nb][r1][c8 * 8] = kb2;
            *(uint4*)&vts[nb][r0][c8 * 8] = va;
            *(uint4*)&vts[nb][r1][c8 * 8] = vb2;
        }

        float rmax[4];
#pragma unroll
        for (int r = 0; r < 4; ++r)
            rmax[r] = fmaxf(fmaxf(s[0][r], s[1][r]), fmaxf(s[2][r], s[3][r]));
#pragma unroll
        for (int msk = 1; msk <= 8; msk <<= 1)
#pragma unroll
            for (int r = 0; r < 4; ++r)
                rmax[r] = fmaxf(rmax[r], __shfl_xor(rmax[r], msk));
        float alpha[4];
#pragma unroll
        for (int r = 0; r < 4; ++r) {
            float mnew = fmaxf(m_run[r], rmax[r]);
            alpha[r] = __expf(m_run[r] - mnew);
            m_run[r] = mnew;
            l_run[r] *= alpha[r];
        }
#pragma unroll
        for (int dt = 0; dt < 4; ++dt)
#pragma unroll
            for (int r = 0; r < 4; ++r) oacc[dt][r] *= alpha[r];

        float lsum[4] = {0.f, 0.f, 0.f, 0.f};
#pragma unroll
        for (int mt = 0; mt < 4; ++mt)
#pragma unroll
            for (int r = 0; r < 4; ++r) {
                float p = __expf(s[mt][r] - m_run[r]);
                s[mt][r] = p;
                lsum[r] += p;
            }
#pragma unroll
        for (int msk = 1; msk <= 8; msk <<= 1)
#pragma unroll
            for (int r = 0; r < 4; ++r) lsum[r] += __shfl_xor(lsum[r], msk);
#pragma unroll
        for (int r = 0; r < 4; ++r) l_run[r] += lsum[r];

#pragma unroll
        for (int mt = 0; mt < 4; ++mt)
#pragma unroll
            for (int r = 0; r < 4; ++r)
                pts[wave][quad * 4 + r][mt * 16 + l16] = f2u(s[mt][r]);

        __syncthreads();

        short8v pa0 = *(const short8v*)&pts[wave][l16][quad * 8];
        short8v pa1 = *(const short8v*)&pts[wave][l16][32 + quad * 8];
#pragma unroll
        for (int dt = 0; dt < 4; ++dt) {
            short8v v0 = *(const short8v*)&vts[cur][dt * 16 + l16][quad * 8];
            oacc[dt] = __builtin_amdgcn_mfma_f32_16x16x32_bf16(pa0, v0, oacc[dt], 0, 0, 0);
            short8v v1 = *(const short8v*)&vts[cur][dt * 16 + l16][32 + quad * 8];
            oacc[dt] = __builtin_amdgcn_mfma_f32_16x16x32_bf16(pa1, v1, oacc[dt], 0, 0, 0);
        }
    }

    float inv[4];
#pragma unroll
    for (int r = 0; r < 4; ++r) inv[r] = 1.f / l_run[r];
    u16* ob = newv + (size_t)b * LL * 512 + h * 64;
#pragma unroll
    for (int dt = 0; dt < 4; ++dt)
#pragma unroll
        for (int r = 0; r < 4; ++r) {
            int w = w0 + quad * 4 + r;
            ob[(size_t)w * 512 + dt * 16 + l16] = f2u(oacc[dt][r] * inv[r]);
        }
}

// -------------------------------------------------------------------------
// Kernel 3: m = swish(newv @ fc_w^T + fc_b); out = layernorm(2x + m)
// -------------------------------------------------------------------------
__global__ __launch_bounds__(256) void fc_ln_kernel(
    const u16* __restrict__ newv,    // [B*L][512] bf16
    const u16* __restrict__ fcw,     // [512][512] bf16
    const u16* __restrict__ fcb,     // [512]
    const u16* __restrict__ x,       // [B][L][D] bf16 canonical
    void* __restrict__ out,          // bf16 or f32 per flag
    const int* __restrict__ flagp)
{
    const int bl = blockIdx.x;     // b*L + l
    const int tid = threadIdx.x;
    __shared__ float nv[512];
    __shared__ float ssum[4], ssq[4];

    nv[tid]       = b2f(newv[(size_t)bl * 512 + tid]);
    nv[tid + 256] = b2f(newv[(size_t)bl * 512 + tid + 256]);
    __syncthreads();

    float r[2];
#pragma unroll
    for (int c = 0; c < 2; ++c) {
        int dout = c * 256 + tid;
        const u16* wr = fcw + (size_t)dout * 512;
        float a = 0.f;
        for (int j = 0; j < 512; j += 8) {
            uint4 p = *(const uint4*)(wr + j);
            float f[8];
            unpack8(p, f);
#pragma unroll
            for (int q = 0; q < 8; ++q) a = fmaf(f[q], nv[j + q], a);
        }
        a += b2f(fcb[dout]);
        float sw = a / (1.f + __expf(-a));        // swish
        float xv = b2f(x[(size_t)bl * 512 + dout]);
        r[c] = xv * 2.f + sw;
    }

    float s  = r[0] + r[1];
    float sq = r[0] * r[0] + r[1] * r[1];
#pragma unroll
    for (int mask = 32; mask >= 1; mask >>= 1) {
        s  += __shfl_xor(s, mask);
        sq += __shfl_xor(sq, mask);
    }
    const int lane = tid & 63, wid = tid >> 6;
    if (lane == 0) { ssum[wid] = s; ssq[wid] = sq; }
    __syncthreads();
    s  = ssum[0] + ssum[1] + ssum[2] + ssum[3];
    sq = ssq[0] + ssq[1] + ssq[2] + ssq[3];
    float mu  = s * (1.f / 512.f);
    float var = sq * (1.f / 512.f) - mu * mu;
    float inv = rsqrtf(var + 1e-5f);

    const int flag = *flagp;
#pragma unroll
    for (int c = 0; c < 2; ++c) {
        int dout = c * 256 + tid;
        float val = (r[c] - mu) * inv;
        if (flag) ((float*)out)[(size_t)bl * 512 + dout] = val;
        else      ((u16*)out)[(size_t)bl * 512 + dout] = f2u(val);
    }
}

extern "C" void kernel_launch(void* const* d_in, const int* in_sizes, int n_in,
                              void* d_out, int out_size, void* d_ws, size_t ws_size,
                              hipStream_t stream) {
    (void)in_sizes; (void)n_in; (void)out_size; (void)ws_size;

    char* ws = (char*)d_ws;
    int* flag = (int*)ws;
    u16* xc   = (u16*)(ws + 256);        // 4,194,304 B -> ends 4,194,560
    u16* wtc  = (u16*)(ws + 4194560);    // [1536][1536] 4,718,592 B -> ends 8,913,152
    u16* bc   = (u16*)(ws + 8913152);    // 3,072 B -> ends 8,916,224
    u16* fwc  = (u16*)(ws + 8916224);    // 524,288 B -> ends 9,440,512
    u16* fbc  = (u16*)(ws + 9440512);    // 1,024 B -> ends 9,441,536
    u16* qkb  = (u16*)(ws + 9441536);    // [16][2][2048][64] = 8 MB -> ends 17,830,144
    u16* vb   = (u16*)(ws + 17830144);   // [16][64][2048]    = 4 MB -> ends 22,024,448
    u16* nvc  = (u16*)(ws + 22024448);   // [2][2048][512]    = 4 MB -> ends 26,218,752

    detect_kernel<<<dim3(1), dim3(64), 0, stream>>>((const u16*)d_in[0], flag);

    convert_kernel<<<dim3((XN + 2047) / 2048), dim3(256), 0, stream>>>(d_in[0], xc,  XN,  flag);
    convw_kernel<<<dim3(1152), dim3(256), 0, stream>>>(d_in[1], wtc, flag);
    convert_kernel<<<dim3((BN + 2047) / 2048), dim3(256), 0, stream>>>(d_in[2], bc,  BN,  flag);
    convert_kernel<<<dim3((FWN + 2047) / 2048), dim3(256), 0, stream>>>(d_in[3], fwc, FWN, flag);
    convert_kernel<<<dim3((FBN + 2047) / 2048), dim3(256), 0, stream>>>(d_in[4], fbc, FBN, flag);

    conv_mfma_kernel<<<dim3(32 * 12), dim3(256), 0, stream>>>(xc, wtc, bc, qkb, vb);
    attn_mfma_kernel<<<dim3(BB * HH * (LL / 64)), dim3(256), 0, stream>>>(qkb, vb, nvc);
    fc_ln_kernel<<<dim3(BB * LL), dim3(256), 0, stream>>>(nvc, fwc, fbc, xc, d_out, flag);
}

// Round 5
// 307.776 us; speedup vs baseline: 14.2310x; 1.7715x over previous
//
#include <hip/hip_runtime.h>
#include <hip/hip_bf16.h>

// Problem constants
#define BB 2
#define LL 2048
#define DD 512
#define HH 8
#define HDM 64
#define SCALE 0.022097086912079608f   // 1/sqrt(2048)

typedef __hip_bfloat16 bf16;
typedef unsigned short u16;
typedef __attribute__((ext_vector_type(8))) short short8v;   // 8 bf16 (4 VGPRs)
typedef __attribute__((ext_vector_type(4))) float float4v;   // 4 fp32 acc

// Input element counts
#define XN  2097152    // 2*2048*512
#define WN  2359296    // 1536*512*3
#define BN  1536
#define FWN 262144     // 512*512
#define FBN 512

__device__ __forceinline__ float b2f(u16 u) {
    return __uint_as_float(((unsigned int)u) << 16);
}
__device__ __forceinline__ u16 f2u(float f) {
    bf16 h = __float2bfloat16(f);
    u16 r;
    __builtin_memcpy(&r, &h, 2);
    return r;
}
__device__ __forceinline__ void unpack8(uint4 p, float* f) {
    f[0] = __uint_as_float(p.x << 16); f[1] = __uint_as_float(p.x & 0xffff0000u);
    f[2] = __uint_as_float(p.y << 16); f[3] = __uint_as_float(p.y & 0xffff0000u);
    f[4] = __uint_as_float(p.z << 16); f[5] = __uint_as_float(p.z & 0xffff0000u);
    f[6] = __uint_as_float(p.w << 16); f[7] = __uint_as_float(p.w & 0xffff0000u);
}
__device__ __forceinline__ uint4 pack8(const float* f) {
    uint4 p;
    p.x = (unsigned)f2u(f[0]) | ((unsigned)f2u(f[1]) << 16);
    p.y = (unsigned)f2u(f[2]) | ((unsigned)f2u(f[3]) << 16);
    p.z = (unsigned)f2u(f[4]) | ((unsigned)f2u(f[5]) << 16);
    p.w = (unsigned)f2u(f[6]) | ((unsigned)f2u(f[7]) << 16);
    return p;
}

// -------------------------------------------------------------------------
// Kernel 0: dtype detect (f32 vs bf16 inputs). See R1 notes.
// -------------------------------------------------------------------------
__global__ void detect_kernel(const u16* __restrict__ x, int* __restrict__ flag) {
    int bad = 0;
    for (int i = threadIdx.x; i < 256; i += 64) {
        float v = b2f(x[i]);
        if (!(fabsf(v) < 100.f)) bad = 1;   // catches NaN too
    }
    unsigned long long m = __ballot(bad);
    if (threadIdx.x == 0) *flag = (m != 0ull) ? 1 : 0;
}

// -------------------------------------------------------------------------
// Kernel 0b: canonicalize an input tensor to bf16 (copy or f32->bf16).
// -------------------------------------------------------------------------
__global__ __launch_bounds__(256) void convert_kernel(
    const void* __restrict__ src, u16* __restrict__ dst, int n,
    const int* __restrict__ flagp)
{
    const int flag = *flagp;
    int i = (blockIdx.x * 256 + threadIdx.x) * 8;
    if (i >= n) return;
    if (flag) {
        const float* s = (const float*)src;
        float f[8];
        float4 a = *(const float4*)(s + i);
        float4 b = *(const float4*)(s + i + 4);
        f[0] = a.x; f[1] = a.y; f[2] = a.z; f[3] = a.w;
        f[4] = b.x; f[5] = b.y; f[6] = b.z; f[7] = b.w;
        *(uint4*)(dst + i) = pack8(f);
    } else {
        *(uint4*)(dst + i) = *(const uint4*)((const u16*)src + i);
    }
}

// -------------------------------------------------------------------------
// Kernel 0c: cnn_w canonicalize + transpose [o][i][k] -> [o][k*512+i].
// -------------------------------------------------------------------------
__global__ __launch_bounds__(256) void convw_kernel(
    const void* __restrict__ src, u16* __restrict__ wt,
    const int* __restrict__ flagp)
{
    const int flag = *flagp;
    int idx = blockIdx.x * 256 + threadIdx.x;   // < 1536*3*64
    int i8  = idx & 63;
    int rem = idx >> 6;
    int k   = rem % 3;
    int o   = rem / 3;
    float f[8];
    if (flag) {
        const float* s = (const float*)src;
#pragma unroll
        for (int j = 0; j < 8; ++j) f[j] = s[(size_t)o * 1536 + (i8 * 8 + j) * 3 + k];
    } else {
        const u16* s = (const u16*)src;
#pragma unroll
        for (int j = 0; j < 8; ++j) f[j] = b2f(s[(size_t)o * 1536 + (i8 * 8 + j) * 3 + k]);
    }
    *(uint4*)(wt + (size_t)o * 1536 + k * 512 + i8 * 8) = pack8(f);
}

// -------------------------------------------------------------------------
// Kernel 1: conv1d(k=3,pad=1)+bias+swish as MFMA GEMM. (unchanged from R4)
// -------------------------------------------------------------------------
__global__ __launch_bounds__(256) void conv_mfma_kernel(
    const u16* __restrict__ x,      // [B][L][512] bf16 canonical
    const u16* __restrict__ wt,     // [1536][1536] = [o][k*512+i]
    const u16* __restrict__ bias,   // [1536]
    u16* __restrict__ qkbuf,        // [B*H][2][L][64]
    u16* __restrict__ vbuf)         // [B*H][64][L]
{
    __shared__ u16 As[2][128][72];
    __shared__ u16 Bs[2][128][72];

    const int blk = blockIdx.x;          // rt*12 + ct
    const int rt = blk / 12;
    const int ct = blk - rt * 12;
    const int b  = rt >> 4;
    const int l0 = (rt & 15) * 128;
    const int tid  = threadIdx.x;
    const int wave = tid >> 6;
    const int lane = tid & 63;
    const int quad = lane >> 4;
    const int l16  = lane & 15;
    const int wx = wave & 1;             // n half
    const int wy = wave >> 1;            // m half

    const int sr = tid >> 3;             // staging row 0..31 (+32*j)
    const int sc = (tid & 7) * 8;        // staging col offset (elements)

    float4v acc[4][4];
#pragma unroll
    for (int mt = 0; mt < 4; ++mt)
#pragma unroll
        for (int nt = 0; nt < 4; ++nt) acc[mt][nt] = (float4v){0.f, 0.f, 0.f, 0.f};

    uint4 va[4], vb[4];
    auto loadA = [&](int kc, uint4* v4) {
        int slab = kc >> 3;
        int i0 = (kc & 7) * 64;
#pragma unroll
        for (int j = 0; j < 4; ++j) {
            int gl = l0 + sr + j * 32 + slab - 1;
            uint4 z = {0u, 0u, 0u, 0u};
            v4[j] = (gl >= 0 && gl < LL)
                ? *(const uint4*)(x + ((size_t)(b * LL + gl)) * DD + i0 + sc) : z;
        }
    };
    auto loadB = [&](int kc, uint4* v4) {
#pragma unroll
        for (int j = 0; j < 4; ++j)
            v4[j] = *(const uint4*)(wt + (size_t)(ct * 128 + sr + j * 32) * 1536 + kc * 64 + sc);
    };
    auto store = [&](int buf, uint4* a4, uint4* b4) {
#pragma unroll
        for (int j = 0; j < 4; ++j) {
            *(uint4*)&As[buf][sr + j * 32][sc] = a4[j];
            *(uint4*)&Bs[buf][sr + j * 32][sc] = b4[j];
        }
    };

    loadA(0, va); loadB(0, vb);
    store(0, va, vb);

    for (int kc = 0; kc < 24; ++kc) {
        const int cur = kc & 1;
        __syncthreads();

        if (kc < 23) { loadA(kc + 1, va); loadB(kc + 1, vb); }

#pragma unroll
        for (int half = 0; half < 2; ++half) {
            short8v aF[4], bF[4];
#pragma unroll
            for (int mt = 0; mt < 4; ++mt)
                aF[mt] = *(const short8v*)&As[cur][wy * 64 + mt * 16 + l16][half * 32 + quad * 8];
#pragma unroll
            for (int nt = 0; nt < 4; ++nt)
                bF[nt] = *(const short8v*)&Bs[cur][wx * 64 + nt * 16 + l16][half * 32 + quad * 8];
#pragma unroll
            for (int mt = 0; mt < 4; ++mt)
#pragma unroll
                for (int nt = 0; nt < 4; ++nt)
                    acc[mt][nt] = __builtin_amdgcn_mfma_f32_16x16x32_bf16(
                        aF[mt], bF[nt], acc[mt][nt], 0, 0, 0);
        }

        if (kc < 23) store(1 - cur, va, vb);
    }

#pragma unroll
    for (int nt = 0; nt < 4; ++nt) {
        int o = ct * 128 + wx * 64 + nt * 16 + l16;
        float bb = b2f(bias[o]);
        int hh = o / 192;
        int rr = o - hh * 192;
        int t  = rr >> 6;
        int dd = rr & 63;
        int bh = b * HH + hh;
#pragma unroll
        for (int mt = 0; mt < 4; ++mt)
#pragma unroll
            for (int r = 0; r < 4; ++r) {
                int l = l0 + wy * 64 + mt * 16 + quad * 4 + r;
                float y = acc[mt][nt][r] + bb;
                y = y / (1.f + __expf(-y));     // swish
                if (t == 2) {
                    vbuf[((size_t)(bh * HDM + dd)) * LL + l] = f2u(y);
                } else {
                    if (t == 0) y *= SCALE;     // fold score scale into Q
                    qkbuf[((size_t)((bh * 2 + t) * LL + l)) * HDM + dd] = f2u(y);
                }
            }
    }
}

// -------------------------------------------------------------------------
// Kernel 2: MFMA flash attention per (b,h). (unchanged from R3 — verified)
// -------------------------------------------------------------------------
__global__ __launch_bounds__(256) void attn_mfma_kernel(
    const u16* __restrict__ qk,    // [B*H][2][L][64]
    const u16* __restrict__ v,     // [B*H][64][L]
    u16* __restrict__ newv)        // [B][L][512]
{
    __shared__ u16 kts[2][64][72];   // [buf][m][d]
    __shared__ u16 vts[2][64][72];   // [buf][d][m]
    __shared__ u16 pts[4][16][72];   // per-wave P [w][m]

    const int blkid = blockIdx.x;        // bh*32 + wchunk
    const int bh = blkid >> 5;
    const int wc = blkid & 31;
    const int b  = bh >> 3;
    const int h  = bh & 7;
    const int tid  = threadIdx.x;
    const int wave = tid >> 6;
    const int lane = tid & 63;
    const int quad = lane >> 4;
    const int l16  = lane & 15;

    const u16* qbase = qk + ((size_t)(bh * 2 + 0)) * LL * HDM;
    const u16* kbase = qk + ((size_t)(bh * 2 + 1)) * LL * HDM;
    const u16* vbase = v + (size_t)bh * HDM * LL;

    const int w0 = wc * 64 + wave * 16;   // this wave's 16 queries

    short8v qfrag[2];
    qfrag[0] = *(const short8v*)(qbase + (size_t)(w0 + l16) * HDM + quad * 8);
    qfrag[1] = *(const short8v*)(qbase + (size_t)(w0 + l16) * HDM + 32 + quad * 8);

    float4v oacc[4];
#pragma unroll
    for (int dt = 0; dt < 4; ++dt) oacc[dt] = (float4v){0.f, 0.f, 0.f, 0.f};
    float m_run[4], l_run[4];
#pragma unroll
    for (int r = 0; r < 4; ++r) { m_run[r] = -1e30f; l_run[r] = 0.f; }

    const int r0 = tid >> 3;          // rows 0..31
    const int r1 = r0 + 32;           // rows 32..63
    const int c8 = tid & 7;           // 8 uint4 per 64-elem row

    {
        uint4 ka  = *(const uint4*)(kbase + (size_t)r0 * HDM + c8 * 8);
        uint4 kb2 = *(const uint4*)(kbase + (size_t)r1 * HDM + c8 * 8);
        uint4 va  = *(const uint4*)(vbase + (size_t)r0 * LL + c8 * 8);
        uint4 vb2 = *(const uint4*)(vbase + (size_t)r1 * LL + c8 * 8);
        *(uint4*)&kts[0][r0][c8 * 8] = ka;
        *(uint4*)&kts[0][r1][c8 * 8] = kb2;
        *(uint4*)&vts[0][r0][c8 * 8] = va;
        *(uint4*)&vts[0][r1][c8 * 8] = vb2;
    }

    for (int ic = 0; ic < 32; ++ic) {
        const int cur = ic & 1;
        __syncthreads();

        uint4 ka, kb2, va, vb2;
        if (ic < 31) {
            const int m0n = (ic + 1) * 64;
            ka  = *(const uint4*)(kbase + (size_t)(m0n + r0) * HDM + c8 * 8);
            kb2 = *(const uint4*)(kbase + (size_t)(m0n + r1) * HDM + c8 * 8);
            va  = *(const uint4*)(vbase + (size_t)r0 * LL + m0n + c8 * 8);
            vb2 = *(const uint4*)(vbase + (size_t)r1 * LL + m0n + c8 * 8);
        }

        float4v s[4];
#pragma unroll
        for (int mt = 0; mt < 4; ++mt) {
            s[mt] = (float4v){0.f, 0.f, 0.f, 0.f};
            short8v b0 = *(const short8v*)&kts[cur][mt * 16 + l16][quad * 8];
            s[mt] = __builtin_amdgcn_mfma_f32_16x16x32_bf16(qfrag[0], b0, s[mt], 0, 0, 0);
            short8v b1 = *(const short8v*)&kts[cur][mt * 16 + l16][32 + quad * 8];
            s[mt] = __builtin_amdgcn_mfma_f32_16x16x32_bf16(qfrag[1], b1, s[mt], 0, 0, 0);
        }

        if (ic < 31) {
            const int nb = 1 - cur;
            *(uint4*)&kts[nb][r0][c8 * 8] = ka;
            *(uint4*)&kts[nb][r1][c8 * 8] = kb2;
            *(uint4*)&vts[nb][r0][c8 * 8] = va;
            *(uint4*)&vts[nb][r1][c8 * 8] = vb2;
        }

        float rmax[4];
#pragma unroll
        for (int r = 0; r < 4; ++r)
            rmax[r] = fmaxf(fmaxf(s[0][r], s[1][r]), fmaxf(s[2][r], s[3][r]));
#pragma unroll
        for (int msk = 1; msk <= 8; msk <<= 1)
#pragma unroll
            for (int r = 0; r < 4; ++r)
                rmax[r] = fmaxf(rmax[r], __shfl_xor(rmax[r], msk));
        float alpha[4];
#pragma unroll
        for (int r = 0; r < 4; ++r) {
            float mnew = fmaxf(m_run[r], rmax[r]);
            alpha[r] = __expf(m_run[r] - mnew);
            m_run[r] = mnew;
            l_run[r] *= alpha[r];
        }
#pragma unroll
        for (int dt = 0; dt < 4; ++dt)
#pragma unroll
            for (int r = 0; r < 4; ++r) oacc[dt][r] *= alpha[r];

        float lsum[4] = {0.f, 0.f, 0.f, 0.f};
#pragma unroll
        for (int mt = 0; mt < 4; ++mt)
#pragma unroll
            for (int r = 0; r < 4; ++r) {
                float p = __expf(s[mt][r] - m_run[r]);
                s[mt][r] = p;
                lsum[r] += p;
            }
#pragma unroll
        for (int msk = 1; msk <= 8; msk <<= 1)
#pragma unroll
            for (int r = 0; r < 4; ++r) lsum[r] += __shfl_xor(lsum[r], msk);
#pragma unroll
        for (int r = 0; r < 4; ++r) l_run[r] += lsum[r];

#pragma unroll
        for (int mt = 0; mt < 4; ++mt)
#pragma unroll
            for (int r = 0; r < 4; ++r)
                pts[wave][quad * 4 + r][mt * 16 + l16] = f2u(s[mt][r]);

        __syncthreads();

        short8v pa0 = *(const short8v*)&pts[wave][l16][quad * 8];
        short8v pa1 = *(const short8v*)&pts[wave][l16][32 + quad * 8];
#pragma unroll
        for (int dt = 0; dt < 4; ++dt) {
            short8v v0 = *(const short8v*)&vts[cur][dt * 16 + l16][quad * 8];
            oacc[dt] = __builtin_amdgcn_mfma_f32_16x16x32_bf16(pa0, v0, oacc[dt], 0, 0, 0);
            short8v v1 = *(const short8v*)&vts[cur][dt * 16 + l16][32 + quad * 8];
            oacc[dt] = __builtin_amdgcn_mfma_f32_16x16x32_bf16(pa1, v1, oacc[dt], 0, 0, 0);
        }
    }

    float inv[4];
#pragma unroll
    for (int r = 0; r < 4; ++r) inv[r] = 1.f / l_run[r];
    u16* ob = newv + (size_t)b * LL * 512 + h * 64;
#pragma unroll
    for (int dt = 0; dt < 4; ++dt)
#pragma unroll
        for (int r = 0; r < 4; ++r) {
            int w = w0 + quad * 4 + r;
            ob[(size_t)w * 512 + dt * 16 + l16] = f2u(oacc[dt][r] * inv[r]);
        }
}

// -------------------------------------------------------------------------
// Kernel 3: MFMA FC + swish + residual + layernorm, fused.
// C[4096 l][512 dout] = newv @ fcw^T. 256 blocks x 16 rows; 4 waves own
// 128 cols each. A-frags (16 newv rows) preloaded to regs; B-frags read
// 16B/lane directly from global fcw (L2-resident, no LDS staging).
// Epilogue: y=C+b; z=2x+swish(y); LN stats via shfl over the 16-lane col
// group + cross-wave LDS reduce; out dtype per flag.
// -------------------------------------------------------------------------
__global__ __launch_bounds__(256) void fc_ln_mfma_kernel(
    const u16* __restrict__ newv,    // [4096][512] bf16
    const u16* __restrict__ fcw,     // [512][512] bf16
    const u16* __restrict__ fcb,     // [512]
    const u16* __restrict__ x,       // [4096][512] bf16 canonical
    void* __restrict__ out,          // bf16 or f32 per flag
    const int* __restrict__ flagp)
{
    const int l0 = blockIdx.x * 16;
    const int tid  = threadIdx.x;
    const int wave = tid >> 6;
    const int lane = tid & 63;
    const int quad = lane >> 4;
    const int l16  = lane & 15;
    const int col0 = wave * 128;

    __shared__ float psum[4][16], psq[4][16];

    // preload 16 A-frags: A[m=l16][k=kc*32+quad*8+j]
    short8v aF[16];
    const u16* arow = newv + (size_t)(l0 + l16) * 512 + quad * 8;
#pragma unroll
    for (int kc = 0; kc < 16; ++kc)
        aF[kc] = *(const short8v*)(arow + kc * 32);

    float4v acc[8];
#pragma unroll
    for (int nt = 0; nt < 8; ++nt) acc[nt] = (float4v){0.f, 0.f, 0.f, 0.f};

#pragma unroll
    for (int nt = 0; nt < 8; ++nt) {
        const u16* brow = fcw + (size_t)(col0 + nt * 16 + l16) * 512 + quad * 8;
#pragma unroll
        for (int kc = 0; kc < 16; ++kc) {
            short8v bF = *(const short8v*)(brow + kc * 32);
            acc[nt] = __builtin_amdgcn_mfma_f32_16x16x32_bf16(aF[kc], bF, acc[nt], 0, 0, 0);
        }
    }

    // epilogue: bias + swish + residual; accumulate LN stats
    float z[8][4];
    float rs[4] = {0.f, 0.f, 0.f, 0.f}, rq[4] = {0.f, 0.f, 0.f, 0.f};
#pragma unroll
    for (int nt = 0; nt < 8; ++nt) {
        int col = col0 + nt * 16 + l16;
        float bb = b2f(fcb[col]);
#pragma unroll
        for (int r = 0; r < 4; ++r) {
            int row = quad * 4 + r;
            float y = acc[nt][r] + bb;
            float sw = y / (1.f + __expf(-y));    // swish
            float xv = b2f(x[(size_t)(l0 + row) * 512 + col]);
            float zz = xv * 2.f + sw;
            z[nt][r] = zz;
            rs[r] += zz;
            rq[r] += zz * zz;
        }
    }
    // reduce over the 16-lane col group (cols of this wave)
#pragma unroll
    for (int msk = 1; msk <= 8; msk <<= 1)
#pragma unroll
        for (int r = 0; r < 4; ++r) {
            rs[r] += __shfl_xor(rs[r], msk);
            rq[r] += __shfl_xor(rq[r], msk);
        }
    if (l16 == 0) {
#pragma unroll
        for (int r = 0; r < 4; ++r) {
            psum[wave][quad * 4 + r] = rs[r];
            psq[wave][quad * 4 + r]  = rq[r];
        }
    }
    __syncthreads();

    float mu[4], inv[4];
#pragma unroll
    for (int r = 0; r < 4; ++r) {
        int row = quad * 4 + r;
        float s = psum[0][row] + psum[1][row] + psum[2][row] + psum[3][row];
        float q = psq[0][row] + psq[1][row] + psq[2][row] + psq[3][row];
        float m = s * (1.f / 512.f);
        float var = q * (1.f / 512.f) - m * m;
        mu[r] = m;
        inv[r] = rsqrtf(var + 1e-5f);
    }

    const int flag = *flagp;
#pragma unroll
    for (int nt = 0; nt < 8; ++nt) {
        int col = col0 + nt * 16 + l16;
#pragma unroll
        for (int r = 0; r < 4; ++r) {
            int row = quad * 4 + r;
            float val = (z[nt][r] - mu[r]) * inv[r];
            if (flag) ((float*)out)[(size_t)(l0 + row) * 512 + col] = val;
            else      ((u16*)out)[(size_t)(l0 + row) * 512 + col] = f2u(val);
        }
    }
}

extern "C" void kernel_launch(void* const* d_in, const int* in_sizes, int n_in,
                              void* d_out, int out_size, void* d_ws, size_t ws_size,
                              hipStream_t stream) {
    (void)in_sizes; (void)n_in; (void)out_size; (void)ws_size;

    char* ws = (char*)d_ws;
    int* flag = (int*)ws;
    u16* xc   = (u16*)(ws + 256);        // 4,194,304 B -> ends 4,194,560
    u16* wtc  = (u16*)(ws + 4194560);    // [1536][1536] 4,718,592 B -> ends 8,913,152
    u16* bc   = (u16*)(ws + 8913152);    // 3,072 B -> ends 8,916,224
    u16* fwc  = (u16*)(ws + 8916224);    // 524,288 B -> ends 9,440,512
    u16* fbc  = (u16*)(ws + 9440512);    // 1,024 B -> ends 9,441,536
    u16* qkb  = (u16*)(ws + 9441536);    // [16][2][2048][64] = 8 MB -> ends 17,830,144
    u16* vb   = (u16*)(ws + 17830144);   // [16][64][2048]    = 4 MB -> ends 22,024,448
    u16* nvc  = (u16*)(ws + 22024448);   // [2][2048][512]    = 4 MB -> ends 26,218,752

    detect_kernel<<<dim3(1), dim3(64), 0, stream>>>((const u16*)d_in[0], flag);

    convert_kernel<<<dim3((XN + 2047) / 2048), dim3(256), 0, stream>>>(d_in[0], xc,  XN,  flag);
    convw_kernel<<<dim3(1152), dim3(256), 0, stream>>>(d_in[1], wtc, flag);
    convert_kernel<<<dim3((BN + 2047) / 2048), dim3(256), 0, stream>>>(d_in[2], bc,  BN,  flag);
    convert_kernel<<<dim3((FWN + 2047) / 2048), dim3(256), 0, stream>>>(d_in[3], fwc, FWN, flag);
    convert_kernel<<<dim3((FBN + 2047) / 2048), dim3(256), 0, stream>>>(d_in[4], fbc, FBN, flag);

    conv_mfma_kernel<<<dim3(32 * 12), dim3(256), 0, stream>>>(xc, wtc, bc, qkb, vb);
    attn_mfma_kernel<<<dim3(BB * HH * (LL / 64)), dim3(256), 0, stream>>>(qkb, vb, nvc);
    fc_ln_mfma_kernel<<<dim3(256), dim3(256), 0, stream>>>(nvc, fwc, fbc, xc, d_out, flag);
}

// Round 6
// 304.326 us; speedup vs baseline: 14.3923x; 1.0113x over previous
//
#include <hip/hip_runtime.h>
#include <hip/hip_bf16.h>

// Problem constants
#define BB 2
#define LL 2048
#define DD 512
#define HH 8
#define HDM 64
#define SCALE 0.022097086912079608f   // 1/sqrt(2048)

typedef __hip_bfloat16 bf16;
typedef unsigned short u16;
typedef __attribute__((ext_vector_type(8))) short short8v;   // 8 bf16 (4 VGPRs)
typedef __attribute__((ext_vector_type(4))) float float4v;   // 4 fp32 acc

// Input element counts
#define XN  2097152    // 2*2048*512
#define WN  2359296    // 1536*512*3
#define BN  1536
#define FWN 262144     // 512*512
#define FBN 512

__device__ __forceinline__ float b2f(u16 u) {
    return __uint_as_float(((unsigned int)u) << 16);
}
__device__ __forceinline__ u16 f2u(float f) {
    bf16 h = __float2bfloat16(f);
    u16 r;
    __builtin_memcpy(&r, &h, 2);
    return r;
}
__device__ __forceinline__ void unpack8(uint4 p, float* f) {
    f[0] = __uint_as_float(p.x << 16); f[1] = __uint_as_float(p.x & 0xffff0000u);
    f[2] = __uint_as_float(p.y << 16); f[3] = __uint_as_float(p.y & 0xffff0000u);
    f[4] = __uint_as_float(p.z << 16); f[5] = __uint_as_float(p.z & 0xffff0000u);
    f[6] = __uint_as_float(p.w << 16); f[7] = __uint_as_float(p.w & 0xffff0000u);
}
__device__ __forceinline__ uint4 pack8(const float* f) {
    uint4 p;
    p.x = (unsigned)f2u(f[0]) | ((unsigned)f2u(f[1]) << 16);
    p.y = (unsigned)f2u(f[2]) | ((unsigned)f2u(f[3]) << 16);
    p.z = (unsigned)f2u(f[4]) | ((unsigned)f2u(f[5]) << 16);
    p.w = (unsigned)f2u(f[6]) | ((unsigned)f2u(f[7]) << 16);
    return p;
}

// -------------------------------------------------------------------------
// Kernel 0: dtype detect (f32 vs bf16 inputs). See R1 notes.
// -------------------------------------------------------------------------
__global__ void detect_kernel(const u16* __restrict__ x, int* __restrict__ flag) {
    int bad = 0;
    for (int i = threadIdx.x; i < 256; i += 64) {
        float v = b2f(x[i]);
        if (!(fabsf(v) < 100.f)) bad = 1;   // catches NaN too
    }
    unsigned long long m = __ballot(bad);
    if (threadIdx.x == 0) *flag = (m != 0ull) ? 1 : 0;
}

// -------------------------------------------------------------------------
// Kernel 0b: canonicalize an input tensor to bf16 (copy or f32->bf16).
// -------------------------------------------------------------------------
__global__ __launch_bounds__(256) void convert_kernel(
    const void* __restrict__ src, u16* __restrict__ dst, int n,
    const int* __restrict__ flagp)
{
    const int flag = *flagp;
    int i = (blockIdx.x * 256 + threadIdx.x) * 8;
    if (i >= n) return;
    if (flag) {
        const float* s = (const float*)src;
        float f[8];
        float4 a = *(const float4*)(s + i);
        float4 b = *(const float4*)(s + i + 4);
        f[0] = a.x; f[1] = a.y; f[2] = a.z; f[3] = a.w;
        f[4] = b.x; f[5] = b.y; f[6] = b.z; f[7] = b.w;
        *(uint4*)(dst + i) = pack8(f);
    } else {
        *(uint4*)(dst + i) = *(const uint4*)((const u16*)src + i);
    }
}

// -------------------------------------------------------------------------
// Kernel 0c: cnn_w canonicalize + transpose [o][i][k] -> [o][k*512+i].
// -------------------------------------------------------------------------
__global__ __launch_bounds__(256) void convw_kernel(
    const void* __restrict__ src, u16* __restrict__ wt,
    const int* __restrict__ flagp)
{
    const int flag = *flagp;
    int idx = blockIdx.x * 256 + threadIdx.x;   // < 1536*3*64
    int i8  = idx & 63;
    int rem = idx >> 6;
    int k   = rem % 3;
    int o   = rem / 3;
    float f[8];
    if (flag) {
        const float* s = (const float*)src;
#pragma unroll
        for (int j = 0; j < 8; ++j) f[j] = s[(size_t)o * 1536 + (i8 * 8 + j) * 3 + k];
    } else {
        const u16* s = (const u16*)src;
#pragma unroll
        for (int j = 0; j < 8; ++j) f[j] = b2f(s[(size_t)o * 1536 + (i8 * 8 + j) * 3 + k]);
    }
    *(uint4*)(wt + (size_t)o * 1536 + k * 512 + i8 * 8) = pack8(f);
}

// -------------------------------------------------------------------------
// Kernel 1: conv1d(k=3,pad=1)+bias+swish as MFMA GEMM.
// R6: epilogue rewritten — C-tile staged through LDS (aliasing As/Bs) so
// qkbuf writes are 128B-contiguous uint4 rows and vbuf writes are
// 256B-contiguous l-runs. Each 64-aligned col group maps to exactly one
// (bh,t) with full dd range (192 = 3*64).
// -------------------------------------------------------------------------
__global__ __launch_bounds__(256) void conv_mfma_kernel(
    const u16* __restrict__ x,      // [B][L][512] bf16 canonical
    const u16* __restrict__ wt,     // [1536][1536] = [o][k*512+i]
    const u16* __restrict__ bias,   // [1536]
    u16* __restrict__ qkbuf,        // [B*H][2][L][64]
    u16* __restrict__ vbuf)         // [B*H][64][L]
{
    __shared__ u16 smem[36864];     // 73728 B: As|Bs staging, then OT out-tile
    u16* Asb = smem;                // [2][128][72]
    u16* Bsb = smem + 2 * 128 * 72; // [2][128][72]
#define OTS 140
    u16* OT  = smem;                // [128][140] aliased after final sync

    const int blk = blockIdx.x;          // rt*12 + ct
    const int rt = blk / 12;
    const int ct = blk - rt * 12;
    const int b  = rt >> 4;
    const int l0 = (rt & 15) * 128;
    const int tid  = threadIdx.x;
    const int wave = tid >> 6;
    const int lane = tid & 63;
    const int quad = lane >> 4;
    const int l16  = lane & 15;
    const int wx = wave & 1;             // n half
    const int wy = wave >> 1;            // m half

    const int sr = tid >> 3;             // staging row 0..31 (+32*j)
    const int sc = (tid & 7) * 8;        // staging col offset (elements)

    float4v acc[4][4];
#pragma unroll
    for (int mt = 0; mt < 4; ++mt)
#pragma unroll
        for (int nt = 0; nt < 4; ++nt) acc[mt][nt] = (float4v){0.f, 0.f, 0.f, 0.f};

    uint4 va[4], vb[4];
    auto loadA = [&](int kc, uint4* v4) {
        int slab = kc >> 3;
        int i0 = (kc & 7) * 64;
#pragma unroll
        for (int j = 0; j < 4; ++j) {
            int gl = l0 + sr + j * 32 + slab - 1;
            uint4 z = {0u, 0u, 0u, 0u};
            v4[j] = (gl >= 0 && gl < LL)
                ? *(const uint4*)(x + ((size_t)(b * LL + gl)) * DD + i0 + sc) : z;
        }
    };
    auto loadB = [&](int kc, uint4* v4) {
#pragma unroll
        for (int j = 0; j < 4; ++j)
            v4[j] = *(const uint4*)(wt + (size_t)(ct * 128 + sr + j * 32) * 1536 + kc * 64 + sc);
    };
    auto store = [&](int buf, uint4* a4, uint4* b4) {
#pragma unroll
        for (int j = 0; j < 4; ++j) {
            *(uint4*)&Asb[((buf) * 128 + sr + j * 32) * 72 + sc] = a4[j];
            *(uint4*)&Bsb[((buf) * 128 + sr + j * 32) * 72 + sc] = b4[j];
        }
    };

    loadA(0, va); loadB(0, vb);
    store(0, va, vb);

    for (int kc = 0; kc < 24; ++kc) {
        const int cur = kc & 1;
        __syncthreads();

        if (kc < 23) { loadA(kc + 1, va); loadB(kc + 1, vb); }

#pragma unroll
        for (int half = 0; half < 2; ++half) {
            short8v aF[4], bF[4];
#pragma unroll
            for (int mt = 0; mt < 4; ++mt)
                aF[mt] = *(const short8v*)&Asb[(cur * 128 + wy * 64 + mt * 16 + l16) * 72 + half * 32 + quad * 8];
#pragma unroll
            for (int nt = 0; nt < 4; ++nt)
                bF[nt] = *(const short8v*)&Bsb[(cur * 128 + wx * 64 + nt * 16 + l16) * 72 + half * 32 + quad * 8];
#pragma unroll
            for (int mt = 0; mt < 4; ++mt)
#pragma unroll
                for (int nt = 0; nt < 4; ++nt)
                    acc[mt][nt] = __builtin_amdgcn_mfma_f32_16x16x32_bf16(
                        aF[mt], bF[nt], acc[mt][nt], 0, 0, 0);
        }

        if (kc < 23) store(1 - cur, va, vb);
    }

    // ---- epilogue stage 1: bias+swish(+SCALE) in regs -> OT [128 l][128 o]
    __syncthreads();   // all As/Bs reads done; safe to alias as OT
    {
        const int tloc = (ct * 2 + wx) % 3;   // t for this wave's col group
#pragma unroll
        for (int nt = 0; nt < 4; ++nt) {
            int oc = wx * 64 + nt * 16 + l16;           // tile-local col
            float bb = b2f(bias[ct * 128 + oc]);
#pragma unroll
            for (int mt = 0; mt < 4; ++mt)
#pragma unroll
                for (int r = 0; r < 4; ++r) {
                    int lr = wy * 64 + mt * 16 + quad * 4 + r;   // tile-local row
                    float y = acc[mt][nt][r] + bb;
                    y = y / (1.f + __expf(-y));                  // swish
                    if (tloc == 0) y *= SCALE;                   // fold into Q
                    OT[lr * OTS + oc] = f2u(y);
                }
        }
    }
    __syncthreads();

    // ---- epilogue stage 2: coalesced write-out per 64-col group
#pragma unroll
    for (int g = 0; g < 2; ++g) {
        int a  = ct * 2 + g;        // 64-col group index (0..23)
        int t  = a % 3;
        int bh = b * HH + a / 3;
        if (t != 2) {
            // Q/K: [bh][t][l][64] — 8 threads per l-row, uint4 (16 B) each
            u16* base = qkbuf + ((size_t)((bh * 2 + t) * LL + l0)) * HDM;
#pragma unroll
            for (int it = 0; it < 4; ++it) {
                int idx = it * 256 + tid;       // 0..1023
                int l   = idx >> 3;             // 0..127
                int d8  = (idx & 7) * 8;        // 0..56
                uint4 val = *(const uint4*)&OT[l * OTS + g * 64 + d8];
                *(uint4*)(base + (size_t)l * HDM + d8) = val;
            }
        } else {
            // V: [bh][dd][L] — 16 threads per dd-row, uint4 of 8 l each
            u16* base = vbuf + ((size_t)(bh * HDM)) * LL + l0;
#pragma unroll
            for (int it = 0; it < 4; ++it) {
                int idx = it * 256 + tid;       // 0..1023
                int dd  = idx >> 4;             // 0..63
                int l8  = (idx & 15) * 8;       // 0..120
                u16 tmp[8];
#pragma unroll
                for (int j = 0; j < 8; ++j) tmp[j] = OT[(l8 + j) * OTS + g * 64 + dd];
                uint4 val;
                val.x = (unsigned)tmp[0] | ((unsigned)tmp[1] << 16);
                val.y = (unsigned)tmp[2] | ((unsigned)tmp[3] << 16);
                val.z = (unsigned)tmp[4] | ((unsigned)tmp[5] << 16);
                val.w = (unsigned)tmp[6] | ((unsigned)tmp[7] << 16);
                *(uint4*)(base + (size_t)dd * LL + l8) = val;
            }
        }
    }
#undef OTS
}

// -------------------------------------------------------------------------
// Kernel 2: MFMA flash attention per (b,h). (unchanged from R3 — verified)
// -------------------------------------------------------------------------
__global__ __launch_bounds__(256) void attn_mfma_kernel(
    const u16* __restrict__ qk,    // [B*H][2][L][64]
    const u16* __restrict__ v,     // [B*H][64][L]
    u16* __restrict__ newv)        // [B][L][512]
{
    __shared__ u16 kts[2][64][72];   // [buf][m][d]
    __shared__ u16 vts[2][64][72];   // [buf][d][m]
    __shared__ u16 pts[4][16][72];   // per-wave P [w][m]

    const int blkid = blockIdx.x;        // bh*32 + wchunk
    const int bh = blkid >> 5;
    const int wc = blkid & 31;
    const int b  = bh >> 3;
    const int h  = bh & 7;
    const int tid  = threadIdx.x;
    const int wave = tid >> 6;
    const int lane = tid & 63;
    const int quad = lane >> 4;
    const int l16  = lane & 15;

    const u16* qbase = qk + ((size_t)(bh * 2 + 0)) * LL * HDM;
    const u16* kbase = qk + ((size_t)(bh * 2 + 1)) * LL * HDM;
    const u16* vbase = v + (size_t)bh * HDM * LL;

    const int w0 = wc * 64 + wave * 16;   // this wave's 16 queries

    short8v qfrag[2];
    qfrag[0] = *(const short8v*)(qbase + (size_t)(w0 + l16) * HDM + quad * 8);
    qfrag[1] = *(const short8v*)(qbase + (size_t)(w0 + l16) * HDM + 32 + quad * 8);

    float4v oacc[4];
#pragma unroll
    for (int dt = 0; dt < 4; ++dt) oacc[dt] = (float4v){0.f, 0.f, 0.f, 0.f};
    float m_run[4], l_run[4];
#pragma unroll
    for (int r = 0; r < 4; ++r) { m_run[r] = -1e30f; l_run[r] = 0.f; }

    const int r0 = tid >> 3;          // rows 0..31
    const int r1 = r0 + 32;           // rows 32..63
    const int c8 = tid & 7;           // 8 uint4 per 64-elem row

    {
        uint4 ka  = *(const uint4*)(kbase + (size_t)r0 * HDM + c8 * 8);
        uint4 kb2 = *(const uint4*)(kbase + (size_t)r1 * HDM + c8 * 8);
        uint4 va  = *(const uint4*)(vbase + (size_t)r0 * LL + c8 * 8);
        uint4 vb2 = *(const uint4*)(vbase + (size_t)r1 * LL + c8 * 8);
        *(uint4*)&kts[0][r0][c8 * 8] = ka;
        *(uint4*)&kts[0][r1][c8 * 8] = kb2;
        *(uint4*)&vts[0][r0][c8 * 8] = va;
        *(uint4*)&vts[0][r1][c8 * 8] = vb2;
    }

    for (int ic = 0; ic < 32; ++ic) {
        const int cur = ic & 1;
        __syncthreads();

        uint4 ka, kb2, va, vb2;
        if (ic < 31) {
            const int m0n = (ic + 1) * 64;
            ka  = *(const uint4*)(kbase + (size_t)(m0n + r0) * HDM + c8 * 8);
            kb2 = *(const uint4*)(kbase + (size_t)(m0n + r1) * HDM + c8 * 8);
            va  = *(const uint4*)(vbase + (size_t)r0 * LL + m0n + c8 * 8);
            vb2 = *(const uint4*)(vbase + (size_t)r1 * LL + m0n + c8 * 8);
        }

        float4v s[4];
#pragma unroll
        for (int mt = 0; mt < 4; ++mt) {
            s[mt] = (float4v){0.f, 0.f, 0.f, 0.f};
            short8v b0 = *(const short8v*)&kts[cur][mt * 16 + l16][quad * 8];
            s[mt] = __builtin_amdgcn_mfma_f32_16x16x32_bf16(qfrag[0], b0, s[mt], 0, 0, 0);
            short8v b1 = *(const short8v*)&kts[cur][mt * 16 + l16][32 + quad * 8];
            s[mt] = __builtin_amdgcn_mfma_f32_16x16x32_bf16(qfrag[1], b1, s[mt], 0, 0, 0);
        }

        if (ic < 31) {
            const int nb = 1 - cur;
            *(uint4*)&kts[nb][r0][c8 * 8] = ka;
            *(uint4*)&kts[nb][r1][c8 * 8] = kb2;
            *(uint4*)&vts[nb][r0][c8 * 8] = va;
            *(uint4*)&vts[nb][r1][c8 * 8] = vb2;
        }

        float rmax[4];
#pragma unroll
        for (int r = 0; r < 4; ++r)
            rmax[r] = fmaxf(fmaxf(s[0][r], s[1][r]), fmaxf(s[2][r], s[3][r]));
#pragma unroll
        for (int msk = 1; msk <= 8; msk <<= 1)
#pragma unroll
            for (int r = 0; r < 4; ++r)
                rmax[r] = fmaxf(rmax[r], __shfl_xor(rmax[r], msk));
        float alpha[4];
#pragma unroll
        for (int r = 0; r < 4; ++r) {
            float mnew = fmaxf(m_run[r], rmax[r]);
            alpha[r] = __expf(m_run[r] - mnew);
            m_run[r] = mnew;
            l_run[r] *= alpha[r];
        }
#pragma unroll
        for (int dt = 0; dt < 4; ++dt)
#pragma unroll
            for (int r = 0; r < 4; ++r) oacc[dt][r] *= alpha[r];

        float lsum[4] = {0.f, 0.f, 0.f, 0.f};
#pragma unroll
        for (int mt = 0; mt < 4; ++mt)
#pragma unroll
            for (int r = 0; r < 4; ++r) {
                float p = __expf(s[mt][r] - m_run[r]);
                s[mt][r] = p;
                lsum[r] += p;
            }
#pragma unroll
        for (int msk = 1; msk <= 8; msk <<= 1)
#pragma unroll
            for (int r = 0; r < 4; ++r) lsum[r] += __shfl_xor(lsum[r], msk);
#pragma unroll
        for (int r = 0; r < 4; ++r) l_run[r] += lsum[r];

#pragma unroll
        for (int mt = 0; mt < 4; ++mt)
#pragma unroll
            for (int r = 0; r < 4; ++r)
                pts[wave][quad * 4 + r][mt * 16 + l16] = f2u(s[mt][r]);

        __syncthreads();

        short8v pa0 = *(const short8v*)&pts[wave][l16][quad * 8];
        short8v pa1 = *(const short8v*)&pts[wave][l16][32 + quad * 8];
#pragma unroll
        for (int dt = 0; dt < 4; ++dt) {
            short8v v0 = *(const short8v*)&vts[cur][dt * 16 + l16][quad * 8];
            oacc[dt] = __builtin_amdgcn_mfma_f32_16x16x32_bf16(pa0, v0, oacc[dt], 0, 0, 0);
            short8v v1 = *(const short8v*)&vts[cur][dt * 16 + l16][32 + quad * 8];
            oacc[dt] = __builtin_amdgcn_mfma_f32_16x16x32_bf16(pa1, v1, oacc[dt], 0, 0, 0);
        }
    }

    float inv[4];
#pragma unroll
    for (int r = 0; r < 4; ++r) inv[r] = 1.f / l_run[r];
    u16* ob = newv + (size_t)b * LL * 512 + h * 64;
#pragma unroll
    for (int dt = 0; dt < 4; ++dt)
#pragma unroll
        for (int r = 0; r < 4; ++r) {
            int w = w0 + quad * 4 + r;
            ob[(size_t)w * 512 + dt * 16 + l16] = f2u(oacc[dt][r] * inv[r]);
        }
}

// -------------------------------------------------------------------------
// Kernel 3: MFMA FC + swish + residual + layernorm, fused. (unchanged R5)
// -------------------------------------------------------------------------
__global__ __launch_bounds__(256) void fc_ln_mfma_kernel(
    const u16* __restrict__ newv,    // [4096][512] bf16
    const u16* __restrict__ fcw,     // [512][512] bf16
    const u16* __restrict__ fcb,     // [512]
    const u16* __restrict__ x,       // [4096][512] bf16 canonical
    void* __restrict__ out,          // bf16 or f32 per flag
    const int* __restrict__ flagp)
{
    const int l0 = blockIdx.x * 16;
    const int tid  = threadIdx.x;
    const int wave = tid >> 6;
    const int lane = tid & 63;
    const int quad = lane >> 4;
    const int l16  = lane & 15;
    const int col0 = wave * 128;

    __shared__ float psum[4][16], psq[4][16];

    short8v aF[16];
    const u16* arow = newv + (size_t)(l0 + l16) * 512 + quad * 8;
#pragma unroll
    for (int kc = 0; kc < 16; ++kc)
        aF[kc] = *(const short8v*)(arow + kc * 32);

    float4v acc[8];
#pragma unroll
    for (int nt = 0; nt < 8; ++nt) acc[nt] = (float4v){0.f, 0.f, 0.f, 0.f};

#pragma unroll
    for (int nt = 0; nt < 8; ++nt) {
        const u16* brow = fcw + (size_t)(col0 + nt * 16 + l16) * 512 + quad * 8;
#pragma unroll
        for (int kc = 0; kc < 16; ++kc) {
            short8v bF = *(const short8v*)(brow + kc * 32);
            acc[nt] = __builtin_amdgcn_mfma_f32_16x16x32_bf16(aF[kc], bF, acc[nt], 0, 0, 0);
        }
    }

    float z[8][4];
    float rs[4] = {0.f, 0.f, 0.f, 0.f}, rq[4] = {0.f, 0.f, 0.f, 0.f};
#pragma unroll
    for (int nt = 0; nt < 8; ++nt) {
        int col = col0 + nt * 16 + l16;
        float bb = b2f(fcb[col]);
#pragma unroll
        for (int r = 0; r < 4; ++r) {
            int row = quad * 4 + r;
            float y = acc[nt][r] + bb;
            float sw = y / (1.f + __expf(-y));    // swish
            float xv = b2f(x[(size_t)(l0 + row) * 512 + col]);
            float zz = xv * 2.f + sw;
            z[nt][r] = zz;
            rs[r] += zz;
            rq[r] += zz * zz;
        }
    }
#pragma unroll
    for (int msk = 1; msk <= 8; msk <<= 1)
#pragma unroll
        for (int r = 0; r < 4; ++r) {
            rs[r] += __shfl_xor(rs[r], msk);
            rq[r] += __shfl_xor(rq[r], msk);
        }
    if (l16 == 0) {
#pragma unroll
        for (int r = 0; r < 4; ++r) {
            psum[wave][quad * 4 + r] = rs[r];
            psq[wave][quad * 4 + r]  = rq[r];
        }
    }
    __syncthreads();

    float mu[4], inv[4];
#pragma unroll
    for (int r = 0; r < 4; ++r) {
        int row = quad * 4 + r;
        float s = psum[0][row] + psum[1][row] + psum[2][row] + psum[3][row];
        float q = psq[0][row] + psq[1][row] + psq[2][row] + psq[3][row];
        float m = s * (1.f / 512.f);
        float var = q * (1.f / 512.f) - m * m;
        mu[r] = m;
        inv[r] = rsqrtf(var + 1e-5f);
    }

    const int flag = *flagp;
#pragma unroll
    for (int nt = 0; nt < 8; ++nt) {
        int col = col0 + nt * 16 + l16;
#pragma unroll
        for (int r = 0; r < 4; ++r) {
            int row = quad * 4 + r;
            float val = (z[nt][r] - mu[r]) * inv[r];
            if (flag) ((float*)out)[(size_t)(l0 + row) * 512 + col] = val;
            else      ((u16*)out)[(size_t)(l0 + row) * 512 + col] = f2u(val);
        }
    }
}

extern "C" void kernel_launch(void* const* d_in, const int* in_sizes, int n_in,
                              void* d_out, int out_size, void* d_ws, size_t ws_size,
                              hipStream_t stream) {
    (void)in_sizes; (void)n_in; (void)out_size; (void)ws_size;

    char* ws = (char*)d_ws;
    int* flag = (int*)ws;
    u16* xc   = (u16*)(ws + 256);        // 4,194,304 B -> ends 4,194,560
    u16* wtc  = (u16*)(ws + 4194560);    // [1536][1536] 4,718,592 B -> ends 8,913,152
    u16* bc   = (u16*)(ws + 8913152);    // 3,072 B -> ends 8,916,224
    u16* fwc  = (u16*)(ws + 8916224);    // 524,288 B -> ends 9,440,512
    u16* fbc  = (u16*)(ws + 9440512);    // 1,024 B -> ends 9,441,536
    u16* qkb  = (u16*)(ws + 9441536);    // [16][2][2048][64] = 8 MB -> ends 17,830,144
    u16* vb   = (u16*)(ws + 17830144);   // [16][64][2048]    = 4 MB -> ends 22,024,448
    u16* nvc  = (u16*)(ws + 22024448);   // [2][2048][512]    = 4 MB -> ends 26,218,752

    detect_kernel<<<dim3(1), dim3(64), 0, stream>>>((const u16*)d_in[0], flag);

    convert_kernel<<<dim3((XN + 2047) / 2048), dim3(256), 0, stream>>>(d_in[0], xc,  XN,  flag);
    convw_kernel<<<dim3(1152), dim3(256), 0, stream>>>(d_in[1], wtc, flag);
    convert_kernel<<<dim3((BN + 2047) / 2048), dim3(256), 0, stream>>>(d_in[2], bc,  BN,  flag);
    convert_kernel<<<dim3((FWN + 2047) / 2048), dim3(256), 0, stream>>>(d_in[3], fwc, FWN, flag);
    convert_kernel<<<dim3((FBN + 2047) / 2048), dim3(256), 0, stream>>>(d_in[4], fbc, FBN, flag);

    conv_mfma_kernel<<<dim3(32 * 12), dim3(256), 0, stream>>>(xc, wtc, bc, qkb, vb);
    attn_mfma_kernel<<<dim3(BB * HH * (LL / 64)), dim3(256), 0, stream>>>(qkb, vb, nvc);
    fc_ln_mfma_kernel<<<dim3(256), dim3(256), 0, stream>>>(nvc, fwc, fbc, xc, d_out, flag);
}

// Round 7
// 211.113 us; speedup vs baseline: 20.7470x; 1.4415x over previous
//
#include <hip/hip_runtime.h>
#include <hip/hip_bf16.h>

// Problem constants
#define BB 2
#define LL 2048
#define DD 512
#define HH 8
#define HDM 64
#define SCALE 0.022097086912079608f   // 1/sqrt(2048)

typedef __hip_bfloat16 bf16;
typedef unsigned short u16;
typedef __attribute__((ext_vector_type(8))) short short8v;   // 8 bf16 (4 VGPRs)
typedef __attribute__((ext_vector_type(4))) float float4v;   // 4 fp32 acc

// Input element counts
#define XN  2097152    // 2*2048*512
#define WN  2359296    // 1536*512*3
#define BN  1536
#define FWN 262144     // 512*512
#define FBN 512

__device__ __forceinline__ float b2f(u16 u) {
    return __uint_as_float(((unsigned int)u) << 16);
}
__device__ __forceinline__ u16 f2u(float f) {
    bf16 h = __float2bfloat16(f);
    u16 r;
    __builtin_memcpy(&r, &h, 2);
    return r;
}
__device__ __forceinline__ void unpack8(uint4 p, float* f) {
    f[0] = __uint_as_float(p.x << 16); f[1] = __uint_as_float(p.x & 0xffff0000u);
    f[2] = __uint_as_float(p.y << 16); f[3] = __uint_as_float(p.y & 0xffff0000u);
    f[4] = __uint_as_float(p.z << 16); f[5] = __uint_as_float(p.z & 0xffff0000u);
    f[6] = __uint_as_float(p.w << 16); f[7] = __uint_as_float(p.w & 0xffff0000u);
}
__device__ __forceinline__ uint4 pack8(const float* f) {
    uint4 p;
    p.x = (unsigned)f2u(f[0]) | ((unsigned)f2u(f[1]) << 16);
    p.y = (unsigned)f2u(f[2]) | ((unsigned)f2u(f[3]) << 16);
    p.z = (unsigned)f2u(f[4]) | ((unsigned)f2u(f[5]) << 16);
    p.w = (unsigned)f2u(f[6]) | ((unsigned)f2u(f[7]) << 16);
    return p;
}

// async 16-B global -> LDS copy (lds dest = wave-uniform base + lane*16)
__device__ __forceinline__ void gld_lds16(const u16* g, u16* l) {
    __builtin_amdgcn_global_load_lds(
        (const __attribute__((address_space(1))) unsigned int*)g,
        (__attribute__((address_space(3))) unsigned int*)l, 16, 0, 0);
}

// -------------------------------------------------------------------------
// Kernel 0: dtype detect (f32 vs bf16 inputs). See R1 notes.
// -------------------------------------------------------------------------
__global__ void detect_kernel(const u16* __restrict__ x, int* __restrict__ flag) {
    int bad = 0;
    for (int i = threadIdx.x; i < 256; i += 64) {
        float v = b2f(x[i]);
        if (!(fabsf(v) < 100.f)) bad = 1;   // catches NaN too
    }
    unsigned long long m = __ballot(bad);
    if (threadIdx.x == 0) *flag = (m != 0ull) ? 1 : 0;
}

// -------------------------------------------------------------------------
// Kernel 0b: canonicalize a flat input tensor to bf16.
// -------------------------------------------------------------------------
__global__ __launch_bounds__(256) void convert_kernel(
    const void* __restrict__ src, u16* __restrict__ dst, int n,
    const int* __restrict__ flagp)
{
    const int flag = *flagp;
    int i = (blockIdx.x * 256 + threadIdx.x) * 8;
    if (i >= n) return;
    if (flag) {
        const float* s = (const float*)src;
        float f[8];
        float4 a = *(const float4*)(s + i);
        float4 b = *(const float4*)(s + i + 4);
        f[0] = a.x; f[1] = a.y; f[2] = a.z; f[3] = a.w;
        f[4] = b.x; f[5] = b.y; f[6] = b.z; f[7] = b.w;
        *(uint4*)(dst + i) = pack8(f);
    } else {
        *(uint4*)(dst + i) = *(const uint4*)((const u16*)src + i);
    }
}

// -------------------------------------------------------------------------
// Kernel 0b': x -> zero-guard-padded xp[B][2050][512] (rows 0 and 2049 are
// the conv pad rows; data lives at rows 1..2048). Makes the conv A-loader
// branch-free, which global_load_lds requires (no lane predication).
// -------------------------------------------------------------------------
__global__ __launch_bounds__(256) void convert_xpad_kernel(
    const void* __restrict__ src, u16* __restrict__ xp,
    const int* __restrict__ flagp)
{
    const int flag = *flagp;
    int idx = blockIdx.x * 256 + threadIdx.x;     // octet id, < 2*2048*64
    if (idx >= BB * LL * 64) return;
    int b   = idx / (LL * 64);
    int rem = idx - b * (LL * 64);
    int l   = rem >> 6;
    int c8  = (rem & 63) * 8;
    size_t si = ((size_t)(b * LL + l)) * 512 + c8;
    size_t di = ((size_t)(b * 2050 + l + 1)) * 512 + c8;
    if (flag) {
        const float* s = (const float*)src;
        float f[8];
        float4 a = *(const float4*)(s + si);
        float4 bq = *(const float4*)(s + si + 4);
        f[0] = a.x; f[1] = a.y; f[2] = a.z; f[3] = a.w;
        f[4] = bq.x; f[5] = bq.y; f[6] = bq.z; f[7] = bq.w;
        *(uint4*)(xp + di) = pack8(f);
    } else {
        *(uint4*)(xp + di) = *(const uint4*)((const u16*)src + si);
    }
}

__global__ void zeropad_kernel(u16* __restrict__ xp) {
    int t = threadIdx.x;            // 256 threads: 2 batches x 2 rows x 64 octets
    int b = t >> 7;
    int r = (t >> 6) & 1;
    int c8 = (t & 63) * 8;
    size_t off = ((size_t)(b * 2050 + (r ? 2049 : 0))) * 512 + c8;
    uint4 z = {0u, 0u, 0u, 0u};
    *(uint4*)(xp + off) = z;
}

// -------------------------------------------------------------------------
// Kernel 0c: cnn_w canonicalize + transpose [o][i][k] -> [o][k*512+i].
// -------------------------------------------------------------------------
__global__ __launch_bounds__(256) void convw_kernel(
    const void* __restrict__ src, u16* __restrict__ wt,
    const int* __restrict__ flagp)
{
    const int flag = *flagp;
    int idx = blockIdx.x * 256 + threadIdx.x;   // < 1536*3*64
    int i8  = idx & 63;
    int rem = idx >> 6;
    int k   = rem % 3;
    int o   = rem / 3;
    float f[8];
    if (flag) {
        const float* s = (const float*)src;
#pragma unroll
        for (int j = 0; j < 8; ++j) f[j] = s[(size_t)o * 1536 + (i8 * 8 + j) * 3 + k];
    } else {
        const u16* s = (const u16*)src;
#pragma unroll
        for (int j = 0; j < 8; ++j) f[j] = b2f(s[(size_t)o * 1536 + (i8 * 8 + j) * 3 + k]);
    }
    *(uint4*)(wt + (size_t)o * 1536 + k * 512 + i8 * 8) = pack8(f);
}

// -------------------------------------------------------------------------
// Kernel 1: conv1d(k=3,pad=1)+bias+swish as MFMA GEMM, m97-style K-loop.
// global_load_lds(16B) async staging into unpadded [2][128][64] LDS tiles
// (64 KB total -> 2 blocks/CU); 1 barrier per BK=64 chunk; branch-free A
// loads from the zero-guard-padded xp. Epilogue: LDS transpose write-out.
// -------------------------------------------------------------------------
__global__ __launch_bounds__(256) void conv_mfma_kernel(
    const u16* __restrict__ xp,     // [B][2050][512] padded bf16
    const u16* __restrict__ wt,     // [1536][1536] = [o][k*512+i]
    const u16* __restrict__ bias,   // [1536]
    u16* __restrict__ qkbuf,        // [B*H][2][L][64]
    u16* __restrict__ vbuf)         // [B*H][64][L]
{
    __shared__ u16 smem[32768];     // 65536 B
    u16* Asb = smem;                // [2][128][64] unpadded
    u16* Bsb = smem + 2 * 128 * 64; // [2][128][64] unpadded
#define OTS 140
    u16* OT  = smem;                // [128][140] aliased after final sync

    const int blk = blockIdx.x;          // rt*12 + ct
    const int rt = blk / 12;
    const int ct = blk - rt * 12;
    const int b  = rt >> 4;
    const int l0 = (rt & 15) * 128;
    const int tid  = threadIdx.x;
    const int wave = tid >> 6;
    const int lane = tid & 63;
    const int quad = lane >> 4;
    const int l16  = lane & 15;
    const int wx = wave & 1;             // n half
    const int wy = wave >> 1;            // m half

    float4v acc[4][4];
#pragma unroll
    for (int mt = 0; mt < 4; ++mt)
#pragma unroll
        for (int nt = 0; nt < 4; ++nt) acc[mt][nt] = (float4v){0.f, 0.f, 0.f, 0.f};

    // stage chunk kc into buffer buf: each wave stages 32 rows of A and B
    // via 4+4 global_load_lds (8 rows x 64 cols = 1 KB per instruction).
    const int rowW = wave * 32;
    const int lrow = lane >> 3;          // 0..7 within instruction
    const int lcol = (lane & 7) * 8;     // element col chunk
    auto stage = [&](int kc, int buf) {
        const int slab = kc >> 3;                // conv tap k (0..2)
        const int i0   = (kc & 7) * 64;          // input-channel slice
        const u16* ga = xp + ((size_t)(b * 2050 + l0 + rowW + slab + lrow)) * 512 + i0 + lcol;
        const u16* gb = wt + ((size_t)(ct * 128 + rowW + lrow)) * 1536 + kc * 64 + lcol;
        u16* la = Asb + (size_t)(buf * 128 + rowW) * 64;
        u16* lb = Bsb + (size_t)(buf * 128 + rowW) * 64;
#pragma unroll
        for (int j = 0; j < 4; ++j) {
            gld_lds16(ga + (size_t)(j * 8) * 512,  la + (j * 8) * 64);
            gld_lds16(gb + (size_t)(j * 8) * 1536, lb + (j * 8) * 64);
        }
    };

    stage(0, 0);

    for (int kc = 0; kc < 24; ++kc) {
        const int cur = kc & 1;
        __syncthreads();   // drains vmcnt -> chunk kc staged; prev reads done

        if (kc < 23) stage(kc + 1, 1 - cur);

#pragma unroll
        for (int half = 0; half < 2; ++half) {
            short8v aF[4], bF[4];
#pragma unroll
            for (int mt = 0; mt < 4; ++mt)
                aF[mt] = *(const short8v*)&Asb[(size_t)(cur * 128 + wy * 64 + mt * 16 + l16) * 64 + half * 32 + quad * 8];
#pragma unroll
            for (int nt = 0; nt < 4; ++nt)
                bF[nt] = *(const short8v*)&Bsb[(size_t)(cur * 128 + wx * 64 + nt * 16 + l16) * 64 + half * 32 + quad * 8];
#pragma unroll
            for (int mt = 0; mt < 4; ++mt)
#pragma unroll
                for (int nt = 0; nt < 4; ++nt)
                    acc[mt][nt] = __builtin_amdgcn_mfma_f32_16x16x32_bf16(
                        aF[mt], bF[nt], acc[mt][nt], 0, 0, 0);
        }
    }

    // ---- epilogue stage 1: bias+swish(+SCALE) in regs -> OT [128 l][128 o]
    __syncthreads();   // all LDS tile reads done; safe to alias as OT
    {
        const int tloc = (ct * 2 + wx) % 3;   // t for this wave's col group
#pragma unroll
        for (int nt = 0; nt < 4; ++nt) {
            int oc = wx * 64 + nt * 16 + l16;           // tile-local col
            float bb = b2f(bias[ct * 128 + oc]);
#pragma unroll
            for (int mt = 0; mt < 4; ++mt)
#pragma unroll
                for (int r = 0; r < 4; ++r) {
                    int lr = wy * 64 + mt * 16 + quad * 4 + r;   // tile-local row
                    float y = acc[mt][nt][r] + bb;
                    y = y / (1.f + __expf(-y));                  // swish
                    if (tloc == 0) y *= SCALE;                   // fold into Q
                    OT[lr * OTS + oc] = f2u(y);
                }
        }
    }
    __syncthreads();

    // ---- epilogue stage 2: coalesced write-out per 64-col group
#pragma unroll
    for (int g = 0; g < 2; ++g) {
        int a  = ct * 2 + g;        // 64-col group index (0..23)
        int t  = a % 3;
        int bh = b * HH + a / 3;
        if (t != 2) {
            u16* base = qkbuf + ((size_t)((bh * 2 + t) * LL + l0)) * HDM;
#pragma unroll
            for (int it = 0; it < 4; ++it) {
                int idx = it * 256 + tid;       // 0..1023
                int l   = idx >> 3;             // 0..127
                int d8  = (idx & 7) * 8;        // 0..56
                uint4 val = *(const uint4*)&OT[l * OTS + g * 64 + d8];
                *(uint4*)(base + (size_t)l * HDM + d8) = val;
            }
        } else {
            u16* base = vbuf + ((size_t)(bh * HDM)) * LL + l0;
#pragma unroll
            for (int it = 0; it < 4; ++it) {
                int idx = it * 256 + tid;       // 0..1023
                int dd  = idx >> 4;             // 0..63
                int l8  = (idx & 15) * 8;       // 0..120
                u16 tmp[8];
#pragma unroll
                for (int j = 0; j < 8; ++j) tmp[j] = OT[(l8 + j) * OTS + g * 64 + dd];
                uint4 val;
                val.x = (unsigned)tmp[0] | ((unsigned)tmp[1] << 16);
                val.y = (unsigned)tmp[2] | ((unsigned)tmp[3] << 16);
                val.z = (unsigned)tmp[4] | ((unsigned)tmp[5] << 16);
                val.w = (unsigned)tmp[6] | ((unsigned)tmp[7] << 16);
                *(uint4*)(base + (size_t)dd * LL + l8) = val;
            }
        }
    }
#undef OTS
}

// -------------------------------------------------------------------------
// Kernel 2: MFMA flash attention per (b,h). (unchanged from R3 — verified)
// -------------------------------------------------------------------------
__global__ __launch_bounds__(256) void attn_mfma_kernel(
    const u16* __restrict__ qk,    // [B*H][2][L][64]
    const u16* __restrict__ v,     // [B*H][64][L]
    u16* __restrict__ newv)        // [B][L][512]
{
    __shared__ u16 kts[2][64][72];   // [buf][m][d]
    __shared__ u16 vts[2][64][72];   // [buf][d][m]
    __shared__ u16 pts[4][16][72];   // per-wave P [w][m]

    const int blkid = blockIdx.x;        // bh*32 + wchunk
    const int bh = blkid >> 5;
    const int wc = blkid & 31;
    const int b  = bh >> 3;
    const int h  = bh & 7;
    const int tid  = threadIdx.x;
    const int wave = tid >> 6;
    const int lane = tid & 63;
    const int quad = lane >> 4;
    const int l16  = lane & 15;

    const u16* qbase = qk + ((size_t)(bh * 2 + 0)) * LL * HDM;
    const u16* kbase = qk + ((size_t)(bh * 2 + 1)) * LL * HDM;
    const u16* vbase = v + (size_t)bh * HDM * LL;

    const int w0 = wc * 64 + wave * 16;   // this wave's 16 queries

    short8v qfrag[2];
    qfrag[0] = *(const short8v*)(qbase + (size_t)(w0 + l16) * HDM + quad * 8);
    qfrag[1] = *(const short8v*)(qbase + (size_t)(w0 + l16) * HDM + 32 + quad * 8);

    float4v oacc[4];
#pragma unroll
    for (int dt = 0; dt < 4; ++dt) oacc[dt] = (float4v){0.f, 0.f, 0.f, 0.f};
    float m_run[4], l_run[4];
#pragma unroll
    for (int r = 0; r < 4; ++r) { m_run[r] = -1e30f; l_run[r] = 0.f; }

    const int r0 = tid >> 3;          // rows 0..31
    const int r1 = r0 + 32;           // rows 32..63
    const int c8 = tid & 7;           // 8 uint4 per 64-elem row

    {
        uint4 ka  = *(const uint4*)(kbase + (size_t)r0 * HDM + c8 * 8);
        uint4 kb2 = *(const uint4*)(kbase + (size_t)r1 * HDM + c8 * 8);
        uint4 va  = *(const uint4*)(vbase + (size_t)r0 * LL + c8 * 8);
        uint4 vb2 = *(const uint4*)(vbase + (size_t)r1 * LL + c8 * 8);
        *(uint4*)&kts[0][r0][c8 * 8] = ka;
        *(uint4*)&kts[0][r1][c8 * 8] = kb2;
        *(uint4*)&vts[0][r0][c8 * 8] = va;
        *(uint4*)&vts[0][r1][c8 * 8] = vb2;
    }

    for (int ic = 0; ic < 32; ++ic) {
        const int cur = ic & 1;
        __syncthreads();

        uint4 ka, kb2, va, vb2;
        if (ic < 31) {
            const int m0n = (ic + 1) * 64;
            ka  = *(const uint4*)(kbase + (size_t)(m0n + r0) * HDM + c8 * 8);
            kb2 = *(const uint4*)(kbase + (size_t)(m0n + r1) * HDM + c8 * 8);
            va  = *(const uint4*)(vbase + (size_t)r0 * LL + m0n + c8 * 8);
            vb2 = *(const uint4*)(vbase + (size_t)r1 * LL + m0n + c8 * 8);
        }

        float4v s[4];
#pragma unroll
        for (int mt = 0; mt < 4; ++mt) {
            s[mt] = (float4v){0.f, 0.f, 0.f, 0.f};
            short8v b0 = *(const short8v*)&kts[cur][mt * 16 + l16][quad * 8];
            s[mt] = __builtin_amdgcn_mfma_f32_16x16x32_bf16(qfrag[0], b0, s[mt], 0, 0, 0);
            short8v b1 = *(const short8v*)&kts[cur][mt * 16 + l16][32 + quad * 8];
            s[mt] = __builtin_amdgcn_mfma_f32_16x16x32_bf16(qfrag[1], b1, s[mt], 0, 0, 0);
        }

        if (ic < 31) {
            const int nb = 1 - cur;
            *(uint4*)&kts[nb][r0][c8 * 8] = ka;
            *(uint4*)&kts[nb][r1][c8 * 8] = kb2;
            *(uint4*)&vts[nb][r0][c8 * 8] = va;
            *(uint4*)&vts[nb][r1][c8 * 8] = vb2;
        }

        float rmax[4];
#pragma unroll
        for (int r = 0; r < 4; ++r)
            rmax[r] = fmaxf(fmaxf(s[0][r], s[1][r]), fmaxf(s[2][r], s[3][r]));
#pragma unroll
        for (int msk = 1; msk <= 8; msk <<= 1)
#pragma unroll
            for (int r = 0; r < 4; ++r)
                rmax[r] = fmaxf(rmax[r], __shfl_xor(rmax[r], msk));
        float alpha[4];
#pragma unroll
        for (int r = 0; r < 4; ++r) {
            float mnew = fmaxf(m_run[r], rmax[r]);
            alpha[r] = __expf(m_run[r] - mnew);
            m_run[r] = mnew;
            l_run[r] *= alpha[r];
        }
#pragma unroll
        for (int dt = 0; dt < 4; ++dt)
#pragma unroll
            for (int r = 0; r < 4; ++r) oacc[dt][r] *= alpha[r];

        float lsum[4] = {0.f, 0.f, 0.f, 0.f};
#pragma unroll
        for (int mt = 0; mt < 4; ++mt)
#pragma unroll
            for (int r = 0; r < 4; ++r) {
                float p = __expf(s[mt][r] - m_run[r]);
                s[mt][r] = p;
                lsum[r] += p;
            }
#pragma unroll
        for (int msk = 1; msk <= 8; msk <<= 1)
#pragma unroll
            for (int r = 0; r < 4; ++r) lsum[r] += __shfl_xor(lsum[r], msk);
#pragma unroll
        for (int r = 0; r < 4; ++r) l_run[r] += lsum[r];

#pragma unroll
        for (int mt = 0; mt < 4; ++mt)
#pragma unroll
            for (int r = 0; r < 4; ++r)
                pts[wave][quad * 4 + r][mt * 16 + l16] = f2u(s[mt][r]);

        __syncthreads();

        short8v pa0 = *(const short8v*)&pts[wave][l16][quad * 8];
        short8v pa1 = *(const short8v*)&pts[wave][l16][32 + quad * 8];
#pragma unroll
        for (int dt = 0; dt < 4; ++dt) {
            short8v v0 = *(const short8v*)&vts[cur][dt * 16 + l16][quad * 8];
            oacc[dt] = __builtin_amdgcn_mfma_f32_16x16x32_bf16(pa0, v0, oacc[dt], 0, 0, 0);
            short8v v1 = *(const short8v*)&vts[cur][dt * 16 + l16][32 + quad * 8];
            oacc[dt] = __builtin_amdgcn_mfma_f32_16x16x32_bf16(pa1, v1, oacc[dt], 0, 0, 0);
        }
    }

    float inv[4];
#pragma unroll
    for (int r = 0; r < 4; ++r) inv[r] = 1.f / l_run[r];
    u16* ob = newv + (size_t)b * LL * 512 + h * 64;
#pragma unroll
    for (int dt = 0; dt < 4; ++dt)
#pragma unroll
        for (int r = 0; r < 4; ++r) {
            int w = w0 + quad * 4 + r;
            ob[(size_t)w * 512 + dt * 16 + l16] = f2u(oacc[dt][r] * inv[r]);
        }
}

// -------------------------------------------------------------------------
// Kernel 3: MFMA FC + swish + residual + layernorm, fused.
// x now read from padded xp layout ([B][2050][512], data at rows 1..2048).
// -------------------------------------------------------------------------
__global__ __launch_bounds__(256) void fc_ln_mfma_kernel(
    const u16* __restrict__ newv,    // [4096][512] bf16
    const u16* __restrict__ fcw,     // [512][512] bf16
    const u16* __restrict__ fcb,     // [512]
    const u16* __restrict__ xp,      // [B][2050][512] padded bf16
    void* __restrict__ out,          // bf16 or f32 per flag
    const int* __restrict__ flagp)
{
    const int l0 = blockIdx.x * 16;
    const int tid  = threadIdx.x;
    const int wave = tid >> 6;
    const int lane = tid & 63;
    const int quad = lane >> 4;
    const int l16  = lane & 15;
    const int col0 = wave * 128;

    const int bb_ = l0 >> 11;   // batch (16-row tiles never straddle)
    const size_t xbase = ((size_t)(bb_ * 2050 + (l0 & 2047) + 1)) * 512;

    __shared__ float psum[4][16], psq[4][16];

    short8v aF[16];
    const u16* arow = newv + (size_t)(l0 + l16) * 512 + quad * 8;
#pragma unroll
    for (int kc = 0; kc < 16; ++kc)
        aF[kc] = *(const short8v*)(arow + kc * 32);

    float4v acc[8];
#pragma unroll
    for (int nt = 0; nt < 8; ++nt) acc[nt] = (float4v){0.f, 0.f, 0.f, 0.f};

#pragma unroll
    for (int nt = 0; nt < 8; ++nt) {
        const u16* brow = fcw + (size_t)(col0 + nt * 16 + l16) * 512 + quad * 8;
#pragma unroll
        for (int kc = 0; kc < 16; ++kc) {
            short8v bF = *(const short8v*)(brow + kc * 32);
            acc[nt] = __builtin_amdgcn_mfma_f32_16x16x32_bf16(aF[kc], bF, acc[nt], 0, 0, 0);
        }
    }

    float z[8][4];
    float rs[4] = {0.f, 0.f, 0.f, 0.f}, rq[4] = {0.f, 0.f, 0.f, 0.f};
#pragma unroll
    for (int nt = 0; nt < 8; ++nt) {
        int col = col0 + nt * 16 + l16;
        float bb = b2f(fcb[col]);
#pragma unroll
        for (int r = 0; r < 4; ++r) {
            int row = quad * 4 + r;
            float y = acc[nt][r] + bb;
            float sw = y / (1.f + __expf(-y));    // swish
            float xv = b2f(xp[xbase + (size_t)row * 512 + col]);
            float zz = xv * 2.f + sw;
            z[nt][r] = zz;
            rs[r] += zz;
            rq[r] += zz * zz;
        }
    }
#pragma unroll
    for (int msk = 1; msk <= 8; msk <<= 1)
#pragma unroll
        for (int r = 0; r < 4; ++r) {
            rs[r] += __shfl_xor(rs[r], msk);
            rq[r] += __shfl_xor(rq[r], msk);
        }
    if (l16 == 0) {
#pragma unroll
        for (int r = 0; r < 4; ++r) {
            psum[wave][quad * 4 + r] = rs[r];
            psq[wave][quad * 4 + r]  = rq[r];
        }
    }
    __syncthreads();

    float mu[4], inv[4];
#pragma unroll
    for (int r = 0; r < 4; ++r) {
        int row = quad * 4 + r;
        float s = psum[0][row] + psum[1][row] + psum[2][row] + psum[3][row];
        float q = psq[0][row] + psq[1][row] + psq[2][row] + psq[3][row];
        float m = s * (1.f / 512.f);
        float var = q * (1.f / 512.f) - m * m;
        mu[r] = m;
        inv[r] = rsqrtf(var + 1e-5f);
    }

    const int flag = *flagp;
#pragma unroll
    for (int nt = 0; nt < 8; ++nt) {
        int col = col0 + nt * 16 + l16;
#pragma unroll
        for (int r = 0; r < 4; ++r) {
            int row = quad * 4 + r;
            float val = (z[nt][r] - mu[r]) * inv[r];
            if (flag) ((float*)out)[(size_t)(l0 + row) * 512 + col] = val;
            else      ((u16*)out)[(size_t)(l0 + row) * 512 + col] = f2u(val);
        }
    }
}

extern "C" void kernel_launch(void* const* d_in, const int* in_sizes, int n_in,
                              void* d_out, int out_size, void* d_ws, size_t ws_size,
                              hipStream_t stream) {
    (void)in_sizes; (void)n_in; (void)out_size; (void)ws_size;

    char* ws = (char*)d_ws;
    int* flag = (int*)ws;
    u16* xp   = (u16*)(ws + 256);        // [2][2050][512] 4,198,400 B -> ends 4,198,656
    u16* wtc  = (u16*)(ws + 4198656);    // [1536][1536] 4,718,592 B  -> ends 8,917,248
    u16* bc   = (u16*)(ws + 8917248);    // 3,072 B  -> ends 8,920,320
    u16* fwc  = (u16*)(ws + 8920320);    // 524,288 B -> ends 9,444,608
    u16* fbc  = (u16*)(ws + 9444608);    // 1,024 B  -> ends 9,445,632
    u16* qkb  = (u16*)(ws + 9445632);    // [16][2][2048][64] = 8 MB -> ends 17,834,240
    u16* vb   = (u16*)(ws + 17834240);   // [16][64][2048]    = 4 MB -> ends 22,028,544
    u16* nvc  = (u16*)(ws + 22028544);   // [2][2048][512]    = 4 MB -> ends 26,222,848

    detect_kernel<<<dim3(1), dim3(64), 0, stream>>>((const u16*)d_in[0], flag);

    zeropad_kernel<<<dim3(1), dim3(256), 0, stream>>>(xp);
    convert_xpad_kernel<<<dim3((BB * LL * 64 + 255) / 256), dim3(256), 0, stream>>>(d_in[0], xp, flag);
    convw_kernel<<<dim3(1152), dim3(256), 0, stream>>>(d_in[1], wtc, flag);
    convert_kernel<<<dim3((BN + 2047) / 2048), dim3(256), 0, stream>>>(d_in[2], bc,  BN,  flag);
    convert_kernel<<<dim3((FWN + 2047) / 2048), dim3(256), 0, stream>>>(d_in[3], fwc, FWN, flag);
    convert_kernel<<<dim3((FBN + 2047) / 2048), dim3(256), 0, stream>>>(d_in[4], fbc, FBN, flag);

    conv_mfma_kernel<<<dim3(32 * 12), dim3(256), 0, stream>>>(xp, wtc, bc, qkb, vb);
    attn_mfma_kernel<<<dim3(BB * HH * (LL / 64)), dim3(256), 0, stream>>>(qkb, vb, nvc);
    fc_ln_mfma_kernel<<<dim3(256), dim3(256), 0, stream>>>(nvc, fwc, fbc, xp, d_out, flag);
}

// Round 8
// 206.174 us; speedup vs baseline: 21.2439x; 1.0240x over previous
//
#include <hip/hip_runtime.h>
#include <hip/hip_bf16.h>

// Problem constants
#define BB 2
#define LL 2048
#define DD 512
#define HH 8
#define HDM 64
#define SCALE 0.022097086912079608f   // 1/sqrt(2048)

typedef __hip_bfloat16 bf16;
typedef unsigned short u16;
typedef __attribute__((ext_vector_type(8))) short short8v;   // 8 bf16 (4 VGPRs)
typedef __attribute__((ext_vector_type(4))) float float4v;   // 4 fp32 acc

// Input element counts
#define XN  2097152    // 2*2048*512
#define WN  2359296    // 1536*512*3
#define BN  1536
#define FWN 262144     // 512*512
#define FBN 512

__device__ __forceinline__ float b2f(u16 u) {
    return __uint_as_float(((unsigned int)u) << 16);
}
__device__ __forceinline__ u16 f2u(float f) {
    bf16 h = __float2bfloat16(f);
    u16 r;
    __builtin_memcpy(&r, &h, 2);
    return r;
}
__device__ __forceinline__ void unpack8(uint4 p, float* f) {
    f[0] = __uint_as_float(p.x << 16); f[1] = __uint_as_float(p.x & 0xffff0000u);
    f[2] = __uint_as_float(p.y << 16); f[3] = __uint_as_float(p.y & 0xffff0000u);
    f[4] = __uint_as_float(p.z << 16); f[5] = __uint_as_float(p.z & 0xffff0000u);
    f[6] = __uint_as_float(p.w << 16); f[7] = __uint_as_float(p.w & 0xffff0000u);
}
__device__ __forceinline__ uint4 pack8(const float* f) {
    uint4 p;
    p.x = (unsigned)f2u(f[0]) | ((unsigned)f2u(f[1]) << 16);
    p.y = (unsigned)f2u(f[2]) | ((unsigned)f2u(f[3]) << 16);
    p.z = (unsigned)f2u(f[4]) | ((unsigned)f2u(f[5]) << 16);
    p.w = (unsigned)f2u(f[6]) | ((unsigned)f2u(f[7]) << 16);
    return p;
}

// async 16-B global -> LDS copy (lds dest = wave-uniform base + lane*16)
__device__ __forceinline__ void gld_lds16(const u16* g, u16* l) {
    __builtin_amdgcn_global_load_lds(
        (const __attribute__((address_space(1))) unsigned int*)g,
        (__attribute__((address_space(3))) unsigned int*)l, 16, 0, 0);
}

// -------------------------------------------------------------------------
// Kernel 0: dtype detect (f32 vs bf16 inputs). See R1 notes.
// -------------------------------------------------------------------------
__global__ void detect_kernel(const u16* __restrict__ x, int* __restrict__ flag) {
    int bad = 0;
    for (int i = threadIdx.x; i < 256; i += 64) {
        float v = b2f(x[i]);
        if (!(fabsf(v) < 100.f)) bad = 1;   // catches NaN too
    }
    unsigned long long m = __ballot(bad);
    if (threadIdx.x == 0) *flag = (m != 0ull) ? 1 : 0;
}

// -------------------------------------------------------------------------
// Kernel 0b: canonicalize a flat input tensor to bf16.
// -------------------------------------------------------------------------
__global__ __launch_bounds__(256) void convert_kernel(
    const void* __restrict__ src, u16* __restrict__ dst, int n,
    const int* __restrict__ flagp)
{
    const int flag = *flagp;
    int i = (blockIdx.x * 256 + threadIdx.x) * 8;
    if (i >= n) return;
    if (flag) {
        const float* s = (const float*)src;
        float f[8];
        float4 a = *(const float4*)(s + i);
        float4 b = *(const float4*)(s + i + 4);
        f[0] = a.x; f[1] = a.y; f[2] = a.z; f[3] = a.w;
        f[4] = b.x; f[5] = b.y; f[6] = b.z; f[7] = b.w;
        *(uint4*)(dst + i) = pack8(f);
    } else {
        *(uint4*)(dst + i) = *(const uint4*)((const u16*)src + i);
    }
}

// -------------------------------------------------------------------------
// Kernel 0b': x -> zero-guard-padded xp[B][2050][512] (rows 0 and 2049 are
// the conv pad rows; data lives at rows 1..2048).
// -------------------------------------------------------------------------
__global__ __launch_bounds__(256) void convert_xpad_kernel(
    const void* __restrict__ src, u16* __restrict__ xp,
    const int* __restrict__ flagp)
{
    const int flag = *flagp;
    int idx = blockIdx.x * 256 + threadIdx.x;     // octet id, < 2*2048*64
    if (idx >= BB * LL * 64) return;
    int b   = idx / (LL * 64);
    int rem = idx - b * (LL * 64);
    int l   = rem >> 6;
    int c8  = (rem & 63) * 8;
    size_t si = ((size_t)(b * LL + l)) * 512 + c8;
    size_t di = ((size_t)(b * 2050 + l + 1)) * 512 + c8;
    if (flag) {
        const float* s = (const float*)src;
        float f[8];
        float4 a = *(const float4*)(s + si);
        float4 bq = *(const float4*)(s + si + 4);
        f[0] = a.x; f[1] = a.y; f[2] = a.z; f[3] = a.w;
        f[4] = bq.x; f[5] = bq.y; f[6] = bq.z; f[7] = bq.w;
        *(uint4*)(xp + di) = pack8(f);
    } else {
        *(uint4*)(xp + di) = *(const uint4*)((const u16*)src + si);
    }
}

__global__ void zeropad_kernel(u16* __restrict__ xp) {
    int t = threadIdx.x;            // 256 threads: 2 batches x 2 rows x 64 octets
    int b = t >> 7;
    int r = (t >> 6) & 1;
    int c8 = (t & 63) * 8;
    size_t off = ((size_t)(b * 2050 + (r ? 2049 : 0))) * 512 + c8;
    uint4 z = {0u, 0u, 0u, 0u};
    *(uint4*)(xp + off) = z;
}

// -------------------------------------------------------------------------
// Kernel 0c: cnn_w canonicalize + transpose [o][i][k] -> [o][k*512+i].
// -------------------------------------------------------------------------
__global__ __launch_bounds__(256) void convw_kernel(
    const void* __restrict__ src, u16* __restrict__ wt,
    const int* __restrict__ flagp)
{
    const int flag = *flagp;
    int idx = blockIdx.x * 256 + threadIdx.x;   // < 1536*3*64
    int i8  = idx & 63;
    int rem = idx >> 6;
    int k   = rem % 3;
    int o   = rem / 3;
    float f[8];
    if (flag) {
        const float* s = (const float*)src;
#pragma unroll
        for (int j = 0; j < 8; ++j) f[j] = s[(size_t)o * 1536 + (i8 * 8 + j) * 3 + k];
    } else {
        const u16* s = (const u16*)src;
#pragma unroll
        for (int j = 0; j < 8; ++j) f[j] = b2f(s[(size_t)o * 1536 + (i8 * 8 + j) * 3 + k]);
    }
    *(uint4*)(wt + (size_t)o * 1536 + k * 512 + i8 * 8) = pack8(f);
}

// -------------------------------------------------------------------------
// Kernel 1: conv GEMM, m97-style K-loop + XOR bank swizzle.
// LDS rows are unpadded (global_load_lds constraint); row r's chunk g is
// stored at chunk g^(r&7) (swizzle applied on the GLOBAL address side),
// restoring uniform bank load on frag reads.
// -------------------------------------------------------------------------
__global__ __launch_bounds__(256) void conv_mfma_kernel(
    const u16* __restrict__ xp,     // [B][2050][512] padded bf16
    const u16* __restrict__ wt,     // [1536][1536] = [o][k*512+i]
    const u16* __restrict__ bias,   // [1536]
    u16* __restrict__ qkbuf,        // [B*H][2][L][64]
    u16* __restrict__ vbuf)         // [B*H][64][L]
{
    __shared__ u16 smem[32768];     // 65536 B
    u16* Asb = smem;                // [2][128][64] unpadded, swizzled
    u16* Bsb = smem + 2 * 128 * 64; // [2][128][64] unpadded, swizzled
#define OTS 140
    u16* OT  = smem;                // [128][140] aliased after final sync

    const int blk = blockIdx.x;          // rt*12 + ct
    const int rt = blk / 12;
    const int ct = blk - rt * 12;
    const int b  = rt >> 4;
    const int l0 = (rt & 15) * 128;
    const int tid  = threadIdx.x;
    const int wave = tid >> 6;
    const int lane = tid & 63;
    const int quad = lane >> 4;
    const int l16  = lane & 15;
    const int e7   = l16 & 7;
    const int wx = wave & 1;             // n half
    const int wy = wave >> 1;            // m half

    float4v acc[4][4];
#pragma unroll
    for (int mt = 0; mt < 4; ++mt)
#pragma unroll
        for (int nt = 0; nt < 4; ++nt) acc[mt][nt] = (float4v){0.f, 0.f, 0.f, 0.f};

    // staging: wave stages 32 rows of A and B; 8 rows / instruction.
    // swizzle: lane with (lrow, c) loads global chunk g = c ^ lrow.
    const int rowW = wave * 32;
    const int lrow = lane >> 3;          // 0..7
    const int g8   = (((lane & 7) ^ lrow)) * 8;
    auto stage = [&](int kc, int buf) {
        const int slab = kc >> 3;                // conv tap k (0..2)
        const int i0   = (kc & 7) * 64;          // input-channel slice
        const u16* ga = xp + ((size_t)(b * 2050 + l0 + rowW + slab + lrow)) * 512 + i0 + g8;
        const u16* gb = wt + ((size_t)(ct * 128 + rowW + lrow)) * 1536 + kc * 64 + g8;
        u16* la = Asb + (size_t)(buf * 128 + rowW) * 64;
        u16* lb = Bsb + (size_t)(buf * 128 + rowW) * 64;
#pragma unroll
        for (int j = 0; j < 4; ++j) {
            gld_lds16(ga + (size_t)(j * 8) * 512,  la + (j * 8) * 64);
            gld_lds16(gb + (size_t)(j * 8) * 1536, lb + (j * 8) * 64);
        }
    };

    stage(0, 0);

    for (int kc = 0; kc < 24; ++kc) {
        const int cur = kc & 1;
        __syncthreads();   // drains vmcnt -> chunk kc staged; prev reads done

        if (kc < 23) stage(kc + 1, 1 - cur);

#pragma unroll
        for (int half = 0; half < 2; ++half) {
            const int p = ((half * 4 + quad) ^ e7) * 8;   // swizzled chunk
            short8v aF[4], bF[4];
#pragma unroll
            for (int mt = 0; mt < 4; ++mt)
                aF[mt] = *(const short8v*)&Asb[(size_t)(cur * 128 + wy * 64 + mt * 16 + l16) * 64 + p];
#pragma unroll
            for (int nt = 0; nt < 4; ++nt)
                bF[nt] = *(const short8v*)&Bsb[(size_t)(cur * 128 + wx * 64 + nt * 16 + l16) * 64 + p];
#pragma unroll
            for (int mt = 0; mt < 4; ++mt)
#pragma unroll
                for (int nt = 0; nt < 4; ++nt)
                    acc[mt][nt] = __builtin_amdgcn_mfma_f32_16x16x32_bf16(
                        aF[mt], bF[nt], acc[mt][nt], 0, 0, 0);
        }
    }

    // ---- epilogue stage 1: bias+swish(+SCALE) in regs -> OT [128 l][128 o]
    __syncthreads();   // all LDS tile reads done; safe to alias as OT
    {
        const int tloc = (ct * 2 + wx) % 3;   // t for this wave's col group
#pragma unroll
        for (int nt = 0; nt < 4; ++nt) {
            int oc = wx * 64 + nt * 16 + l16;           // tile-local col
            float bb = b2f(bias[ct * 128 + oc]);
#pragma unroll
            for (int mt = 0; mt < 4; ++mt)
#pragma unroll
                for (int r = 0; r < 4; ++r) {
                    int lr = wy * 64 + mt * 16 + quad * 4 + r;   // tile-local row
                    float y = acc[mt][nt][r] + bb;
                    y = y / (1.f + __expf(-y));                  // swish
                    if (tloc == 0) y *= SCALE;                   // fold into Q
                    OT[lr * OTS + oc] = f2u(y);
                }
        }
    }
    __syncthreads();

    // ---- epilogue stage 2: coalesced write-out per 64-col group
#pragma unroll
    for (int g = 0; g < 2; ++g) {
        int a  = ct * 2 + g;        // 64-col group index (0..23)
        int t  = a % 3;
        int bh = b * HH + a / 3;
        if (t != 2) {
            u16* base = qkbuf + ((size_t)((bh * 2 + t) * LL + l0)) * HDM;
#pragma unroll
            for (int it = 0; it < 4; ++it) {
                int idx = it * 256 + tid;       // 0..1023
                int l   = idx >> 3;             // 0..127
                int d8  = (idx & 7) * 8;        // 0..56
                uint4 val = *(const uint4*)&OT[l * OTS + g * 64 + d8];
                *(uint4*)(base + (size_t)l * HDM + d8) = val;
            }
        } else {
            u16* base = vbuf + ((size_t)(bh * HDM)) * LL + l0;
#pragma unroll
            for (int it = 0; it < 4; ++it) {
                int idx = it * 256 + tid;       // 0..1023
                int dd  = idx >> 4;             // 0..63
                int l8  = (idx & 15) * 8;       // 0..120
                u16 tmp[8];
#pragma unroll
                for (int j = 0; j < 8; ++j) tmp[j] = OT[(l8 + j) * OTS + g * 64 + dd];
                uint4 val;
                val.x = (unsigned)tmp[0] | ((unsigned)tmp[1] << 16);
                val.y = (unsigned)tmp[2] | ((unsigned)tmp[3] << 16);
                val.z = (unsigned)tmp[4] | ((unsigned)tmp[5] << 16);
                val.w = (unsigned)tmp[6] | ((unsigned)tmp[7] << 16);
                *(uint4*)(base + (size_t)dd * LL + l8) = val;
            }
        }
    }
#undef OTS
}

// -------------------------------------------------------------------------
// Kernel 2: MFMA flash attention per (b,h).
// R8: global_load_lds staging (swizzled, unpadded [64][64] tiles), ONE
// barrier per chunk (pts is per-wave: same-wave lgkmcnt ordering suffices),
// pts stride 76 (conflict-free writes).
// -------------------------------------------------------------------------
__global__ __launch_bounds__(256) void attn_mfma_kernel(
    const u16* __restrict__ qk,    // [B*H][2][L][64]
    const u16* __restrict__ v,     // [B*H][64][L]
    u16* __restrict__ newv)        // [B][L][512]
{
    __shared__ u16 kts[2][64][64];   // [buf][m][d] swizzled
    __shared__ u16 vts[2][64][64];   // [buf][d][m] swizzled
    __shared__ u16 pts[4][16][76];   // per-wave P [w][m], padded stride

    const int blkid = blockIdx.x;        // bh*32 + wchunk
    const int bh = blkid >> 5;
    const int wc = blkid & 31;
    const int b  = bh >> 3;
    const int h  = bh & 7;
    const int tid  = threadIdx.x;
    const int wave = tid >> 6;
    const int lane = tid & 63;
    const int quad = lane >> 4;
    const int l16  = lane & 15;
    const int e7   = l16 & 7;

    const u16* qbase = qk + ((size_t)(bh * 2 + 0)) * LL * HDM;
    const u16* kbase = qk + ((size_t)(bh * 2 + 1)) * LL * HDM;
    const u16* vbase = v + (size_t)bh * HDM * LL;

    const int w0 = wc * 64 + wave * 16;   // this wave's 16 queries

    short8v qfrag[2];
    qfrag[0] = *(const short8v*)(qbase + (size_t)(w0 + l16) * HDM + quad * 8);
    qfrag[1] = *(const short8v*)(qbase + (size_t)(w0 + l16) * HDM + 32 + quad * 8);

    float4v oacc[4];
#pragma unroll
    for (int dt = 0; dt < 4; ++dt) oacc[dt] = (float4v){0.f, 0.f, 0.f, 0.f};
    float m_run[4], l_run[4];
#pragma unroll
    for (int r = 0; r < 4; ++r) { m_run[r] = -1e30f; l_run[r] = 0.f; }

    // staging: wave stages 16 K rows + 16 V rows per chunk (2+2 instrs).
    const int rbase = wave * 16;
    const int lrow  = lane >> 3;          // 0..7
    const int g8    = ((lane & 7) ^ lrow) * 8;
    auto stage = [&](int ic, int buf) {
        const int m0 = ic * 64;
#pragma unroll
        for (int j = 0; j < 2; ++j) {
            gld_lds16(kbase + (size_t)(m0 + rbase + j * 8 + lrow) * HDM + g8,
                      &kts[buf][rbase + j * 8][0]);
            gld_lds16(vbase + (size_t)(rbase + j * 8 + lrow) * LL + m0 + g8,
                      &vts[buf][rbase + j * 8][0]);
        }
    };

    stage(0, 0);

    for (int ic = 0; ic < 32; ++ic) {
        const int cur = ic & 1;
        __syncthreads();   // drains vmcnt -> chunk ic staged; prev reads done

        if (ic < 31) stage(ic + 1, 1 - cur);

        const int p0 = (quad ^ e7) * 8;         // swizzled chunk, k-half 0
        const int p1 = ((quad + 4) ^ e7) * 8;   // k-half 1

        float4v s[4];
#pragma unroll
        for (int mt = 0; mt < 4; ++mt) {
            s[mt] = (float4v){0.f, 0.f, 0.f, 0.f};
            short8v b0 = *(const short8v*)&kts[cur][mt * 16 + l16][p0];
            s[mt] = __builtin_amdgcn_mfma_f32_16x16x32_bf16(qfrag[0], b0, s[mt], 0, 0, 0);
            short8v b1 = *(const short8v*)&kts[cur][mt * 16 + l16][p1];
            s[mt] = __builtin_amdgcn_mfma_f32_16x16x32_bf16(qfrag[1], b1, s[mt], 0, 0, 0);
        }

        float rmax[4];
#pragma unroll
        for (int r = 0; r < 4; ++r)
            rmax[r] = fmaxf(fmaxf(s[0][r], s[1][r]), fmaxf(s[2][r], s[3][r]));
#pragma unroll
        for (int msk = 1; msk <= 8; msk <<= 1)
#pragma unroll
            for (int r = 0; r < 4; ++r)
                rmax[r] = fmaxf(rmax[r], __shfl_xor(rmax[r], msk));
        float alpha[4];
#pragma unroll
        for (int r = 0; r < 4; ++r) {
            float mnew = fmaxf(m_run[r], rmax[r]);
            alpha[r] = __expf(m_run[r] - mnew);
            m_run[r] = mnew;
            l_run[r] *= alpha[r];
        }
#pragma unroll
        for (int dt = 0; dt < 4; ++dt)
#pragma unroll
            for (int r = 0; r < 4; ++r) oacc[dt][r] *= alpha[r];

        float lsum[4] = {0.f, 0.f, 0.f, 0.f};
#pragma unroll
        for (int mt = 0; mt < 4; ++mt)
#pragma unroll
            for (int r = 0; r < 4; ++r) {
                float p = __expf(s[mt][r] - m_run[r]);
                s[mt][r] = p;
                lsum[r] += p;
            }
#pragma unroll
        for (int msk = 1; msk <= 8; msk <<= 1)
#pragma unroll
            for (int r = 0; r < 4; ++r) lsum[r] += __shfl_xor(lsum[r], msk);
#pragma unroll
        for (int r = 0; r < 4; ++r) l_run[r] += lsum[r];

        // P: C-layout -> per-wave LDS tile (same-wave: no block barrier)
#pragma unroll
        for (int mt = 0; mt < 4; ++mt)
#pragma unroll
            for (int r = 0; r < 4; ++r)
                pts[wave][quad * 4 + r][mt * 16 + l16] = f2u(s[mt][r]);

        short8v pa0 = *(const short8v*)&pts[wave][l16][quad * 8];
        short8v pa1 = *(const short8v*)&pts[wave][l16][32 + quad * 8];
#pragma unroll
        for (int dt = 0; dt < 4; ++dt) {
            short8v v0 = *(const short8v*)&vts[cur][dt * 16 + l16][p0];
            oacc[dt] = __builtin_amdgcn_mfma_f32_16x16x32_bf16(pa0, v0, oacc[dt], 0, 0, 0);
            short8v v1 = *(const short8v*)&vts[cur][dt * 16 + l16][p1];
            oacc[dt] = __builtin_amdgcn_mfma_f32_16x16x32_bf16(pa1, v1, oacc[dt], 0, 0, 0);
        }
    }

    float inv[4];
#pragma unroll
    for (int r = 0; r < 4; ++r) inv[r] = 1.f / l_run[r];
    u16* ob = newv + (size_t)b * LL * 512 + h * 64;
#pragma unroll
    for (int dt = 0; dt < 4; ++dt)
#pragma unroll
        for (int r = 0; r < 4; ++r) {
            int w = w0 + quad * 4 + r;
            ob[(size_t)w * 512 + dt * 16 + l16] = f2u(oacc[dt][r] * inv[r]);
        }
}

// -------------------------------------------------------------------------
// Kernel 3: MFMA FC + swish + residual + layernorm, fused. (unchanged R7)
// -------------------------------------------------------------------------
__global__ __launch_bounds__(256) void fc_ln_mfma_kernel(
    const u16* __restrict__ newv,    // [4096][512] bf16
    const u16* __restrict__ fcw,     // [512][512] bf16
    const u16* __restrict__ fcb,     // [512]
    const u16* __restrict__ xp,      // [B][2050][512] padded bf16
    void* __restrict__ out,          // bf16 or f32 per flag
    const int* __restrict__ flagp)
{
    const int l0 = blockIdx.x * 16;
    const int tid  = threadIdx.x;
    const int wave = tid >> 6;
    const int lane = tid & 63;
    const int quad = lane >> 4;
    const int l16  = lane & 15;
    const int col0 = wave * 128;

    const int bb_ = l0 >> 11;   // batch (16-row tiles never straddle)
    const size_t xbase = ((size_t)(bb_ * 2050 + (l0 & 2047) + 1)) * 512;

    __shared__ float psum[4][16], psq[4][16];

    short8v aF[16];
    const u16* arow = newv + (size_t)(l0 + l16) * 512 + quad * 8;
#pragma unroll
    for (int kc = 0; kc < 16; ++kc)
        aF[kc] = *(const short8v*)(arow + kc * 32);

    float4v acc[8];
#pragma unroll
    for (int nt = 0; nt < 8; ++nt) acc[nt] = (float4v){0.f, 0.f, 0.f, 0.f};

#pragma unroll
    for (int nt = 0; nt < 8; ++nt) {
        const u16* brow = fcw + (size_t)(col0 + nt * 16 + l16) * 512 + quad * 8;
#pragma unroll
        for (int kc = 0; kc < 16; ++kc) {
            short8v bF = *(const short8v*)(brow + kc * 32);
            acc[nt] = __builtin_amdgcn_mfma_f32_16x16x32_bf16(aF[kc], bF, acc[nt], 0, 0, 0);
        }
    }

    float z[8][4];
    float rs[4] = {0.f, 0.f, 0.f, 0.f}, rq[4] = {0.f, 0.f, 0.f, 0.f};
#pragma unroll
    for (int nt = 0; nt < 8; ++nt) {
        int col = col0 + nt * 16 + l16;
        float bb = b2f(fcb[col]);
#pragma unroll
        for (int r = 0; r < 4; ++r) {
            int row = quad * 4 + r;
            float y = acc[nt][r] + bb;
            float sw = y / (1.f + __expf(-y));    // swish
            float xv = b2f(xp[xbase + (size_t)row * 512 + col]);
            float zz = xv * 2.f + sw;
            z[nt][r] = zz;
            rs[r] += zz;
            rq[r] += zz * zz;
        }
    }
#pragma unroll
    for (int msk = 1; msk <= 8; msk <<= 1)
#pragma unroll
        for (int r = 0; r < 4; ++r) {
            rs[r] += __shfl_xor(rs[r], msk);
            rq[r] += __shfl_xor(rq[r], msk);
        }
    if (l16 == 0) {
#pragma unroll
        for (int r = 0; r < 4; ++r) {
            psum[wave][quad * 4 + r] = rs[r];
            psq[wave][quad * 4 + r]  = rq[r];
        }
    }
    __syncthreads();

    float mu[4], inv[4];
#pragma unroll
    for (int r = 0; r < 4; ++r) {
        int row = quad * 4 + r;
        float s = psum[0][row] + psum[1][row] + psum[2][row] + psum[3][row];
        float q = psq[0][row] + psq[1][row] + psq[2][row] + psq[3][row];
        float m = s * (1.f / 512.f);
        float var = q * (1.f / 512.f) - m * m;
        mu[r] = m;
        inv[r] = rsqrtf(var + 1e-5f);
    }

    const int flag = *flagp;
#pragma unroll
    for (int nt = 0; nt < 8; ++nt) {
        int col = col0 + nt * 16 + l16;
#pragma unroll
        for (int r = 0; r < 4; ++r) {
            int row = quad * 4 + r;
            float val = (z[nt][r] - mu[r]) * inv[r];
            if (flag) ((float*)out)[(size_t)(l0 + row) * 512 + col] = val;
            else      ((u16*)out)[(size_t)(l0 + row) * 512 + col] = f2u(val);
        }
    }
}

extern "C" void kernel_launch(void* const* d_in, const int* in_sizes, int n_in,
                              void* d_out, int out_size, void* d_ws, size_t ws_size,
                              hipStream_t stream) {
    (void)in_sizes; (void)n_in; (void)out_size; (void)ws_size;

    char* ws = (char*)d_ws;
    int* flag = (int*)ws;
    u16* xp   = (u16*)(ws + 256);        // [2][2050][512] 4,198,400 B -> ends 4,198,656
    u16* wtc  = (u16*)(ws + 4198656);    // [1536][1536] 4,718,592 B  -> ends 8,917,248
    u16* bc   = (u16*)(ws + 8917248);    // 3,072 B  -> ends 8,920,320
    u16* fwc  = (u16*)(ws + 8920320);    // 524,288 B -> ends 9,444,608
    u16* fbc  = (u16*)(ws + 9444608);    // 1,024 B  -> ends 9,445,632
    u16* qkb  = (u16*)(ws + 9445632);    // [16][2][2048][64] = 8 MB -> ends 17,834,240
    u16* vb   = (u16*)(ws + 17834240);   // [16][64][2048]    = 4 MB -> ends 22,028,544
    u16* nvc  = (u16*)(ws + 22028544);   // [2][2048][512]    = 4 MB -> ends 26,222,848

    detect_kernel<<<dim3(1), dim3(64), 0, stream>>>((const u16*)d_in[0], flag);

    zeropad_kernel<<<dim3(1), dim3(256), 0, stream>>>(xp);
    convert_xpad_kernel<<<dim3((BB * LL * 64 + 255) / 256), dim3(256), 0, stream>>>(d_in[0], xp, flag);
    convw_kernel<<<dim3(1152), dim3(256), 0, stream>>>(d_in[1], wtc, flag);
    convert_kernel<<<dim3((BN + 2047) / 2048), dim3(256), 0, stream>>>(d_in[2], bc,  BN,  flag);
    convert_kernel<<<dim3((FWN + 2047) / 2048), dim3(256), 0, stream>>>(d_in[3], fwc, FWN, flag);
    convert_kernel<<<dim3((FBN + 2047) / 2048), dim3(256), 0, stream>>>(d_in[4], fbc, FBN, flag);

    conv_mfma_kernel<<<dim3(32 * 12), dim3(256), 0, stream>>>(xp, wtc, bc, qkb, vb);
    attn_mfma_kernel<<<dim3(BB * HH * (LL / 64)), dim3(256), 0, stream>>>(qkb, vb, nvc);
    fc_ln_mfma_kernel<<<dim3(256), dim3(256), 0, stream>>>(nvc, fwc, fbc, xp, d_out, flag);
}